// Round 2
// baseline (2172.929 us; speedup 1.0000x reference)
//
#include <hip/hip_runtime.h>
#include <math.h>

#define Bn 2
#define Cn 192
#define Hn 256
#define Wn 256
#define HWn 65536
#define NPIX 25165824   /* 2*192*256*256 */
#define NROW 98304      /* 2*192*256 */
#define NWIN 2048       /* B * 32 * 32 windows */
#define PI_F 3.14159265358979323846f
#define GR 14           /* gaussian spatial tap radius (sigma_s ~ 1.59 px) */

// G mask in unshifted frequency coords: g1d((k+128)%256), separable.
__device__ __forceinline__ float gauss1d(int k) {
  int idx = (k + 128) & 255;
  float t = -128.0f + (float)idx * (256.0f / 255.0f);
  return expf(-(t * t) * (1.0f / 1310.72f));   // 2*cutoff^2 = 2*25.6^2
}

__global__ __launch_bounds__(256) void k_zero(float* p, int n) {
  int i = blockIdx.x * 256 + threadIdx.x;
  if (i < n) p[i] = 0.f;
}

// K_ga: spatial kernel ga[d] = ifft256(g1d)[d] by direct DFT.
// Exact integer phase reduction: angle = 2*pi*((k*d) mod 256)/256.
__global__ __launch_bounds__(256) void k_ga(float2* __restrict__ ga) {
  const int d = threadIdx.x;
  float sr = 0.f, si = 0.f;
  for (int k = 0; k < 256; ++k) {
    float g = gauss1d(k);
    int ph = (k * d) & 255;
    float a = (float)ph * (2.0f * PI_F / 256.0f);
    sr = fmaf(g, cosf(a), sr);
    si = fmaf(g, sinf(a), si);
  }
  ga[d] = make_float2(sr * (1.0f / 256.0f), si * (1.0f / 256.0f));
}

// K1: circular row convolution with complex ga -> tmp[row][x] (float2).
// lp_c = x (*) (ga ⊗ ga); this is the x-direction pass.
__global__ __launch_bounds__(256) void k_rowconv(const float* __restrict__ x,
                                                 const float2* __restrict__ ga,
                                                 float2* __restrict__ tmp) {
  __shared__ float xr[256];
  __shared__ float2 gs[2 * GR + 1];
  const int row = blockIdx.x;          // < 98304
  const int t = threadIdx.x;
  xr[t] = x[(size_t)row * 256 + t];
  if (t < 2 * GR + 1) gs[t] = ga[(t - GR) & 255];
  __syncthreads();
  float sr = 0.f, si = 0.f;
  #pragma unroll
  for (int d = -GR; d <= GR; ++d) {
    float xv = xr[(t - d) & 255];
    float2 g = gs[d + GR];
    sr = fmaf(xv, g.x, sr);
    si = fmaf(xv, g.y, si);
  }
  tmp[(size_t)row * 256 + t] = make_float2(sr, si);
}

// K2: circular column convolution (complex*complex) -> lp_c; lp = |lp_c|;
// hp = |x - lp_c|; channel-attn stats (sum/max of lp) via atomics.
__global__ __launch_bounds__(256) void k_colhp(const float2* __restrict__ tmp,
                                               const float* __restrict__ x,
                                               const float2* __restrict__ ga,
                                               float* __restrict__ hp,
                                               float* __restrict__ ca_sum,
                                               float* __restrict__ ca_max) {
  __shared__ float2 gs[2 * GR + 1];
  __shared__ float rsum[4], rmax[4];
  const int row = blockIdx.x;          // (b,c,y) < 98304
  const int bc = row >> 8, y = row & 255;
  const int t = threadIdx.x;           // x coordinate
  if (t < 2 * GR + 1) gs[t] = ga[(t - GR) & 255];
  __syncthreads();
  const size_t base = (size_t)bc << 16;
  float lr = 0.f, li = 0.f;
  #pragma unroll
  for (int d = -GR; d <= GR; ++d) {
    float2 rv = tmp[base + (size_t)(((y - d) & 255) << 8) + t];
    float2 g = gs[d + GR];
    lr = fmaf(rv.x, g.x, fmaf(-rv.y, g.y, lr));
    li = fmaf(rv.x, g.y, fmaf(rv.y, g.x, li));
  }
  const size_t sp = base + ((size_t)y << 8) + t;
  float xv = x[sp];
  float lp = sqrtf(lr * lr + li * li);
  float hre = xv - lr;
  hp[sp] = sqrtf(hre * hre + li * li);
  float lsum = lp, lmax = lp;
  #pragma unroll
  for (int off = 32; off > 0; off >>= 1) {
    lsum += __shfl_down(lsum, off);
    lmax = fmaxf(lmax, __shfl_down(lmax, off));
  }
  if ((t & 63) == 0) { rsum[t >> 6] = lsum; rmax[t >> 6] = lmax; }
  __syncthreads();
  if (t == 0) {
    float s = rsum[0] + rsum[1] + rsum[2] + rsum[3];
    float m = fmaxf(fmaxf(rmax[0], rmax[1]), fmaxf(rmax[2], rmax[3]));
    atomicAdd(&ca_sum[bc], s);
    atomicMax((int*)&ca_max[bc], __float_as_int(m));
  }
}

// K5: sm[b,0/1,y,x] = mean/max over channels of hp
__global__ __launch_bounds__(256) void k_sm(const float* __restrict__ hp,
                                            float* __restrict__ sm) {
  int p = blockIdx.x * 256 + threadIdx.x;
  int b = p >> 16, s = p & 65535;
  const float* hpb = hp + (size_t)b * Cn * HWn + s;
  float sum = 0.f, mx = 0.f;
  for (int c = 0; c < Cn; ++c) {
    float v = hpb[(size_t)c * HWn];
    sum += v; mx = fmaxf(mx, v);
  }
  sm[(size_t)(b * 2 + 0) * HWn + s] = sum * (1.0f / 192.0f);
  sm[(size_t)(b * 2 + 1) * HWn + s] = mx;
}

// K6: channel attention MLP -> w1[b,c]
__global__ __launch_bounds__(256) void k_chatt(const float* __restrict__ ca_sum,
                                               const float* __restrict__ ca_max,
                                               const float* __restrict__ w1m,
                                               const float* __restrict__ w2m,
                                               float* __restrict__ w1out) {
  __shared__ float hid2[2][2][12];
  int tid = threadIdx.x;
  if (tid < 48) {
    int b = tid / 24, rem = tid % 24, pool = rem / 12, j = rem % 12;
    const float* src = pool ? ca_max : ca_sum;
    float scale = pool ? 1.0f : (1.0f / 65536.0f);
    float acc = 0.f;
    for (int c = 0; c < Cn; ++c) acc += src[b * Cn + c] * scale * w1m[j * Cn + c];
    hid2[b][pool][j] = fmaxf(acc, 0.f);
  }
  __syncthreads();
  for (int u = tid; u < 2 * Cn; u += 256) {
    int b = u / Cn, c = u % Cn;
    float acc = 0.f;
    #pragma unroll
    for (int j = 0; j < 12; ++j)
      acc += (hid2[b][0][j] + hid2[b][1][j]) * w2m[c * 12 + j];
    w1out[b * Cn + c] = 1.0f / (1.0f + expf(-acc));
  }
}

// K7: spatial attention -> w2[b,y,x]
__global__ __launch_bounds__(256) void k_spatt(const float* __restrict__ sm,
                                               const float* __restrict__ w3,
                                               const float* __restrict__ w5,
                                               const float* __restrict__ w7,
                                               float* __restrict__ w2out) {
  int p = blockIdx.x * 256 + threadIdx.x;
  int b = p >> 16, s = p & 65535;
  int y = s >> 8, x = s & 255;
  float acc = 0.f;
  for (int ic = 0; ic < 2; ++ic) {
    const float* in = sm + (size_t)(b * 2 + ic) * HWn;
    for (int dy = -3; dy <= 3; ++dy) {
      int yy = y + dy; if (yy < 0 || yy > 255) continue;
      for (int dx = -3; dx <= 3; ++dx) {
        int xx = x + dx; if (xx < 0 || xx > 255) continue;
        float v = in[yy * 256 + xx];
        acc += v * w7[ic * 49 + (dy + 3) * 7 + (dx + 3)];
        if (dy >= -2 && dy <= 2 && dx >= -2 && dx <= 2)
          acc += v * w5[ic * 25 + (dy + 2) * 5 + (dx + 2)];
        if (dy >= -1 && dy <= 1 && dx >= -1 && dx <= 1)
          acc += v * w3[ic * 9 + (dy + 1) * 3 + (dx + 1)];
      }
    }
  }
  w2out[p] = 1.0f / (1.0f + expf(-acc));
}

// K8: per-window LayerNorm: x*w1*w2 -> LN over channels -> xn in window-SoA
// layout: xn[w][c][n], w = global window id, n = intra-window pixel (8x8).
__global__ __launch_bounds__(256) void k_ln_w(const float* __restrict__ x,
                                              const float* __restrict__ w1v,
                                              const float* __restrict__ w2v,
                                              const float* __restrict__ lnw,
                                              const float* __restrict__ lnb,
                                              float* __restrict__ xn) {
  __shared__ float xs[Cn][64];
  __shared__ float ps[4][64], pq[4][64], mu[64], inv[64];
  const int blk = blockIdx.x;            // < 2048
  const int b = blk >> 10, wi = blk & 1023;
  const int wy = wi >> 5, wx = wi & 31;
  const int t = threadIdx.x;
  #pragma unroll
  for (int r = 0; r < 12; ++r) {
    int u4 = t + (r << 8);               // < 3072 float4s
    int f = u4 << 2;
    int c = f >> 6, n0 = f & 63;
    int y = (wy << 3) + (n0 >> 3), xx = (wx << 3) + (n0 & 7);
    const float4 xv = *(const float4*)&x[(((size_t)(b * Cn + c)) << 16) + y * 256 + xx];
    const float4 wv = *(const float4*)&w2v[((size_t)b << 16) + y * 256 + xx];
    float w1c = w1v[b * Cn + c];
    float4 v;
    v.x = xv.x * w1c * wv.x; v.y = xv.y * w1c * wv.y;
    v.z = xv.z * w1c * wv.z; v.w = xv.w * w1c * wv.w;
    *(float4*)&xs[c][n0] = v;
  }
  __syncthreads();
  {
    int n = t & 63, part = t >> 6;
    float s = 0.f, ss = 0.f;
    #pragma unroll
    for (int cc = 0; cc < 48; ++cc) {
      float v = xs[part * 48 + cc][n];
      s += v; ss += v * v;
    }
    ps[part][n] = s; pq[part][n] = ss;
  }
  __syncthreads();
  if (t < 64) {
    float s = ps[0][t] + ps[1][t] + ps[2][t] + ps[3][t];
    float q = pq[0][t] + pq[1][t] + pq[2][t] + pq[3][t];
    float m = s * (1.0f / 192.0f);
    float var = q * (1.0f / 192.0f) - m * m;
    mu[t] = m; inv[t] = rsqrtf(var + 1e-5f);
  }
  __syncthreads();
  float* outp = xn + (size_t)blk * 12288;
  #pragma unroll
  for (int r = 0; r < 12; ++r) {
    int u4 = t + (r << 8);
    int f = u4 << 2;
    int c = f >> 6, n0 = f & 63;
    float4 v = *(float4*)&xs[c][n0];
    float lw = lnw[c], lb = lnb[c];
    float4 o;
    o.x = (v.x - mu[n0 + 0]) * inv[n0 + 0] * lw + lb;
    o.y = (v.y - mu[n0 + 1]) * inv[n0 + 1] * lw + lb;
    o.z = (v.z - mu[n0 + 2]) * inv[n0 + 2] * lw + lb;
    o.w = (v.w - mu[n0 + 3]) * inv[n0 + 3] * lw + lb;
    *(float4*)&outp[f] = o;
  }
}

// K_bias: rel-pos MLP bias table [NH][64][64]
__global__ __launch_bounds__(256) void k_bias(const float* __restrict__ mw1,
                                              const float* __restrict__ mb1,
                                              const float* __restrict__ mw2,
                                              const float* __restrict__ mb2,
                                              float* __restrict__ biasTab) {
  int pair = blockIdx.x * 256 + threadIdx.x;
  int n = pair >> 6, m = pair & 63;
  float dr = (float)((n >> 3) - (m >> 3));
  float dc = (float)((n & 7) - (m & 7));
  float r0 = copysignf(log1pf(fabsf(dr)), dr);
  float r1 = copysignf(log1pf(fabsf(dc)), dc);
  float acc[6];
  #pragma unroll
  for (int h = 0; h < 6; ++h) acc[h] = mb2[h];
  for (int j = 0; j < 256; ++j) {
    float hv = fmaxf(r0 * mw1[j * 2] + r1 * mw1[j * 2 + 1] + mb1[j], 0.f);
    #pragma unroll
    for (int h = 0; h < 6; ++h) acc[h] += hv * mw2[h * 256 + j];
  }
  #pragma unroll
  for (int h = 0; h < 6; ++h) biasTab[h * 4096 + n * 64 + m] = acc[h];
}

// K_wt: transpose the 4 1x1-conv weight matrices to k-major Wt[c][o]
// so a wave's per-k weight slab (24 contiguous o) is one scalar-load run.
__global__ __launch_bounds__(256) void k_wt(const float* __restrict__ qw,
                                            const float* __restrict__ kw,
                                            const float* __restrict__ vw,
                                            const float* __restrict__ pw,
                                            float* __restrict__ wt) {
  int i = blockIdx.x * 256 + threadIdx.x;     // < 4*36864
  int m = i / 36864, r = i - m * 36864;
  int o = r / 192, c = r - o * 192;
  const float* s = (m == 0) ? qw : (m == 1) ? kw : (m == 2) ? vw : pw;
  wt[m * 36864 + c * 192 + o] = s[o * 192 + c];
}

// Core fp32 GEMM micro-loop: wave-uniform weight slab (24 out-ch, k-major,
// scalar-load path via readfirstlane-uniform o0), per-lane pixel from LDS.
// LDS traffic: ONE ds_read_b32 per k per wave vs 48 VALU cyc -> VALU-bound.
__device__ __forceinline__ void gemm24(const float* __restrict__ xsp,
                                       const float* __restrict__ wp,
                                       const float* __restrict__ bias,
                                       int o0, int lane, float acc[24]) {
  #pragma unroll
  for (int i = 0; i < 24; ++i) acc[i] = bias[o0 + i];
  #pragma unroll 2
  for (int k = 0; k < 192; ++k) {
    float xv = xsp[(k << 6) + lane];
    const float4* wr = (const float4*)(wp + k * 192 + o0);   // uniform addr
    #pragma unroll
    for (int j = 0; j < 6; ++j) {
      float4 w4 = wr[j];
      acc[4 * j + 0] = fmaf(w4.x, xv, acc[4 * j + 0]);
      acc[4 * j + 1] = fmaf(w4.y, xv, acc[4 * j + 1]);
      acc[4 * j + 2] = fmaf(w4.z, xv, acc[4 * j + 2]);
      acc[4 * j + 3] = fmaf(w4.w, xv, acc[4 * j + 3]);
    }
  }
}

// K9: fused Q/K/V 1x1-conv GEMMs. One block per window, 512 thr = 8 waves.
// X tile (48KB) staged in LDS once; three k-loops against it.
// wave wv owns out-ch [wv*24, wv*24+24); lane owns one of the 64 pixels.
// Q adds hp (prompt, spatial); V dual-writes SoA + spatial.
// hp / Vsp alias (same buffer): each address is read (Q epi) then written
// (V epi) by the SAME thread -> no __restrict__ on those two, order is safe.
// Vsoa aliases input xn: full tile staged in LDS before any store.
__global__ __launch_bounds__(512) void k_qkv(const float* __restrict__ xn,
                                             const float* __restrict__ wt,
                                             const float* __restrict__ qb,
                                             const float* __restrict__ kb,
                                             const float* __restrict__ vb,
                                             const float* hp,
                                             float* Qo, float* Ko,
                                             float* Vsoa, float* Vsp) {
  __shared__ float xs[12288];
  const int w = blockIdx.x;
  const int b = w >> 10, wi = w & 1023;
  const int wy = wi >> 5, wx = wi & 31;
  const int t = threadIdx.x;
  const float4* src = (const float4*)(xn + (size_t)w * 12288);
  #pragma unroll
  for (int r = 0; r < 6; ++r) {
    int u4 = t + (r << 9);
    ((float4*)xs)[u4] = src[u4];
  }
  __syncthreads();
  const int lane = t & 63;
  const int wv = __builtin_amdgcn_readfirstlane(t >> 6);
  const int o0 = wv * 24;
  const int y = (wy << 3) + (lane >> 3), xxp = (wx << 3) + (lane & 7);
  const int sOff = y * 256 + xxp;
  const size_t soa = (size_t)w * 12288 + (size_t)o0 * 64 + lane;
  const size_t sp = (((size_t)(b * Cn + o0)) << 16) + sOff;
  float acc[24];
  // ---- Q = conv1x1 + prompt(hp) ----
  gemm24(xs, wt, qb, o0, lane, acc);
  #pragma unroll
  for (int i = 0; i < 24; ++i)
    Qo[soa + (size_t)(i << 6)] = acc[i] + hp[sp + ((size_t)i << 16)];
  // ---- K ----
  gemm24(xs, wt + 36864, kb, o0, lane, acc);
  #pragma unroll
  for (int i = 0; i < 24; ++i)
    Ko[soa + (size_t)(i << 6)] = acc[i];
  // ---- V (SoA + spatial) ----
  gemm24(xs, wt + 2 * 36864, vb, o0, lane, acc);
  #pragma unroll
  for (int i = 0; i < 24; ++i) {
    Vsoa[soa + (size_t)(i << 6)] = acc[i];
    Vsp[sp + ((size_t)i << 16)] = acc[i];
  }
}

// K12: proj GEMM. Input tile = attn_out(SoA) + conv_out(spatial) staged in
// LDS; identity epilogue (+ x*w1*w2); spatial output.
__global__ __launch_bounds__(512) void k_proj(const float* __restrict__ attn,
                                              const float* __restrict__ conv,
                                              const float* __restrict__ wtp,
                                              const float* __restrict__ pb,
                                              const float* __restrict__ resx,
                                              const float* __restrict__ rw1,
                                              const float* __restrict__ rw2,
                                              float* __restrict__ out) {
  __shared__ float xs[12288];
  const int w = blockIdx.x;
  const int b = w >> 10, wi = w & 1023;
  const int wy = wi >> 5, wx = wi & 31;
  const int t = threadIdx.x;
  const float4* av = (const float4*)(attn + (size_t)w * 12288);
  #pragma unroll
  for (int r = 0; r < 6; ++r) {
    int u4 = t + (r << 9);
    int f = u4 << 2;
    int c = f >> 6, n0 = f & 63;
    int yy = (wy << 3) + (n0 >> 3), xx = (wx << 3) + (n0 & 7);
    float4 a = av[u4];
    float4 cv = *(const float4*)&conv[(((size_t)(b * Cn + c)) << 16) + yy * 256 + xx];
    a.x += cv.x; a.y += cv.y; a.z += cv.z; a.w += cv.w;
    ((float4*)xs)[u4] = a;
  }
  __syncthreads();
  const int lane = t & 63;
  const int wv = __builtin_amdgcn_readfirstlane(t >> 6);
  const int o0 = wv * 24;
  const int y = (wy << 3) + (lane >> 3), xxp = (wx << 3) + (lane & 7);
  const int sOff = y * 256 + xxp;
  float acc[24];
  gemm24(xs, wtp, pb, o0, lane, acc);
  const float w2s = rw2[((size_t)b << 16) + sOff];
  const size_t sp = (((size_t)(b * Cn + o0)) << 16) + sOff;
  #pragma unroll
  for (int i = 0; i < 24; ++i) {
    float idv = resx[sp + ((size_t)i << 16)] * rw1[b * Cn + o0 + i] * w2s;
    out[sp + ((size_t)i << 16)] = acc[i] + idv;
  }
}

// K10: window attention, one block per (window, head). All tensors window-SoA.
// out may alias V (block fully stages q/k/v in LDS before storing).
__global__ __launch_bounds__(256) void k_attn(const float* Q,
                                              const float* Kt,
                                              const float* V,
                                              const float* __restrict__ biasTab,
                                              float* out) {
  __shared__ float qt[64][36];     // [n][d], padded
  __shared__ float kt[64][36];     // [m][d]
  __shared__ float vl[2048];       // [d][m] flat
  __shared__ float pb[64][65];     // bias tile then softmax probs [n][m]
  const int blk = blockIdx.x;      // < 2048*6
  const int h = blk % 6, w = blk / 6;
  const int t = threadIdx.x;
  const size_t base = ((size_t)w * Cn + h * 32) * 64;
  const float4* Qg = (const float4*)(Q + base);
  const float4* Kg = (const float4*)(Kt + base);
  const float4* Vg = (const float4*)(V + base);
  #pragma unroll
  for (int r = 0; r < 2; ++r) {
    int i4 = t + (r << 8);          // < 512
    int f = i4 << 2;
    int d = f >> 6, n = f & 63;
    float4 q4 = Qg[i4], k4 = Kg[i4], v4 = Vg[i4];
    qt[n + 0][d] = q4.x * 0.17677669529663687f;
    qt[n + 1][d] = q4.y * 0.17677669529663687f;
    qt[n + 2][d] = q4.z * 0.17677669529663687f;
    qt[n + 3][d] = q4.w * 0.17677669529663687f;
    kt[n + 0][d] = k4.x; kt[n + 1][d] = k4.y;
    kt[n + 2][d] = k4.z; kt[n + 3][d] = k4.w;
    ((float4*)vl)[i4] = v4;
  }
  const float4* Bg = (const float4*)(biasTab + h * 4096);
  #pragma unroll
  for (int r = 0; r < 4; ++r) {
    int i4 = t + (r << 8);          // < 1024
    int f = i4 << 2;
    int n = f >> 6, m = f & 63;
    float4 b4 = Bg[i4];
    pb[n][m + 0] = b4.x; pb[n][m + 1] = b4.y;
    pb[n][m + 2] = b4.z; pb[n][m + 3] = b4.w;
  }
  __syncthreads();
  // ---- QK^T + bias: thread (n = t>>2, 16 m's = (t&3)*16+j) ----
  const int n = t >> 2, m0 = (t & 3) << 4;
  float sc[16];
  #pragma unroll
  for (int j = 0; j < 16; ++j) sc[j] = pb[n][m0 + j];
  #pragma unroll
  for (int d4 = 0; d4 < 32; d4 += 4) {
    float4 qv = *(const float4*)&qt[n][d4];
    #pragma unroll
    for (int j = 0; j < 16; ++j) {
      float4 kv = *(const float4*)&kt[m0 + j][d4];
      sc[j] += qv.x * kv.x + qv.y * kv.y + qv.z * kv.z + qv.w * kv.w;
    }
  }
  // ---- softmax across the 4 lanes sharing row n ----
  float mx = sc[0];
  #pragma unroll
  for (int j = 1; j < 16; ++j) mx = fmaxf(mx, sc[j]);
  mx = fmaxf(mx, __shfl_xor(mx, 1));
  mx = fmaxf(mx, __shfl_xor(mx, 2));
  float ssum = 0.f;
  #pragma unroll
  for (int j = 0; j < 16; ++j) { sc[j] = __expf(sc[j] - mx); ssum += sc[j]; }
  ssum += __shfl_xor(ssum, 1);
  ssum += __shfl_xor(ssum, 2);
  float sinv = 1.0f / ssum;
  #pragma unroll
  for (int j = 0; j < 16; ++j) sc[j] *= sinv;
  __syncthreads();   // all bias reads done before overwrite
  #pragma unroll
  for (int j = 0; j < 16; ++j) pb[n][m0 + j] = sc[j];
  __syncthreads();
  // ---- PV: thread (nn = t&63, 8 d's = (t>>6)*8..) ----
  const int nn = t & 63, dp = (t >> 6) << 3;
  float o[8];
  #pragma unroll
  for (int dd = 0; dd < 8; ++dd) o[dd] = 0.f;
  #pragma unroll
  for (int mc = 0; mc < 16; ++mc) {
    int m = mc << 2;
    float p0 = pb[nn][m], p1 = pb[nn][m + 1], p2 = pb[nn][m + 2], p3 = pb[nn][m + 3];
    #pragma unroll
    for (int dd = 0; dd < 8; ++dd) {
      float4 vv = *(const float4*)&vl[((dp + dd) << 6) + m];
      o[dd] += p0 * vv.x + p1 * vv.y + p2 * vv.z + p3 * vv.w;
    }
  }
  #pragma unroll
  for (int dd = 0; dd < 8; ++dd)
    out[base + (size_t)(dp + dd) * 64 + nn] = o[dd];
}

// K11: depthwise 5x5 reflect conv on spatial V -> conv_out (spatial)
__global__ __launch_bounds__(256) void k_dw(const float* __restrict__ V,
                                            const float* __restrict__ dww,
                                            const float* __restrict__ dwb,
                                            float* __restrict__ co) {
  size_t idx = (size_t)blockIdx.x * 256 + threadIdx.x;
  int s = (int)(idx & 65535);
  int bc = (int)(idx >> 16);
  int c = bc % Cn;
  int y = s >> 8, x = s & 255;
  const float* vb = V + ((size_t)bc << 16);
  float acc = dwb[c];
  #pragma unroll
  for (int dy = -2; dy <= 2; ++dy) {
    int yy = y + dy;
    yy = yy < 0 ? -yy : (yy > 255 ? 510 - yy : yy);
    #pragma unroll
    for (int dx = -2; dx <= 2; ++dx) {
      int xx = x + dx;
      xx = xx < 0 ? -xx : (xx > 255 ? 510 - xx : xx);
      acc += vb[yy * 256 + xx] * dww[c * 25 + (dy + 2) * 5 + (dx + 2)];
    }
  }
  co[idx] = acc;
}

extern "C" void kernel_launch(void* const* d_in, const int* in_sizes, int n_in,
                              void* d_out, int out_size, void* d_ws, size_t ws_size,
                              hipStream_t stream) {
  const float* x      = (const float*)d_in[0];
  const float* ln_w   = (const float*)d_in[1];
  const float* ln_b   = (const float*)d_in[2];
  const float* ca_w1  = (const float*)d_in[3];
  const float* ca_w2  = (const float*)d_in[4];
  const float* sa_w3  = (const float*)d_in[5];
  const float* sa_w5  = (const float*)d_in[6];
  const float* sa_w7  = (const float*)d_in[7];
  const float* q_w    = (const float*)d_in[8];
  const float* q_b    = (const float*)d_in[9];
  const float* k_w    = (const float*)d_in[10];
  const float* k_b    = (const float*)d_in[11];
  const float* v_w    = (const float*)d_in[12];
  const float* v_b    = (const float*)d_in[13];
  const float* proj_w = (const float*)d_in[14];
  const float* proj_b = (const float*)d_in[15];
  const float* meta_w1 = (const float*)d_in[16];
  const float* meta_b1 = (const float*)d_in[17];
  const float* meta_w2 = (const float*)d_in[18];
  const float* meta_b2 = (const float*)d_in[19];
  const float* dw_w   = (const float*)d_in[20];
  const float* dw_b   = (const float*)d_in[21];

  float* ws = (float*)d_ws;
  const size_t N = (size_t)NPIX;
  // Overlay (peak 3N + small):
  //  buf0+buf1: tmp (complex row-conv, 2N floats) -> then
  //  buf0: xn(SoA) -> V-SoA (in-place) -> attn_out (in-place)
  //  buf1: K(SoA)  -> conv_out (spatial)
  //  buf2: hp (spatial) -> V-spatial (per-window thread-local RAW, safe)
  //  d_out: Q(SoA) -> final output (spatial)
  float* buf0 = ws;
  float* buf1 = ws + N;
  float* buf2 = ws + 2 * N;
  float* smallb = ws + 3 * N;
  float* ca_sum  = smallb;
  float* ca_max  = smallb + 384;
  float* w1v     = smallb + 768;
  float* smb     = smallb + 1152;
  float* w2v     = smb + 262144;
  float* biasTab = w2v + 131072;
  float* wt4     = biasTab + 24576;   // 4 * 192*192 transposed weights
  float* gaBuf   = wt4 + 147456;      // 256 complex spatial gaussian taps

  float2* tmp = (float2*)buf0;        // spans buf0+buf1
  float* hp = buf2;
  float* xn = buf0;
  float* Kb = buf1;
  float* Qb = (float*)d_out;
  float* Vsoa = buf0;
  float* Vsp  = buf2;
  float* attn_out = buf0;
  float* conv_out = buf1;

  k_zero<<<3, 256, 0, stream>>>(ca_sum, 768);
  k_ga<<<1, 256, 0, stream>>>((float2*)gaBuf);
  k_rowconv<<<NROW, 256, 0, stream>>>(x, (const float2*)gaBuf, tmp);
  k_colhp<<<NROW, 256, 0, stream>>>(tmp, x, (const float2*)gaBuf, hp, ca_sum, ca_max);
  k_sm<<<Bn * HWn / 256, 256, 0, stream>>>(hp, smb);
  k_chatt<<<1, 256, 0, stream>>>(ca_sum, ca_max, ca_w1, ca_w2, w1v);
  k_spatt<<<Bn * HWn / 256, 256, 0, stream>>>(smb, sa_w3, sa_w5, sa_w7, w2v);
  k_ln_w<<<NWIN, 256, 0, stream>>>(x, w1v, w2v, ln_w, ln_b, xn);
  k_bias<<<16, 256, 0, stream>>>(meta_w1, meta_b1, meta_w2, meta_b2, biasTab);
  k_wt<<<576, 256, 0, stream>>>(q_w, k_w, v_w, proj_w, wt4);
  // fused Q/K/V: Q(+hp)->d_out, K->buf1, V->buf0(in-place)+buf2(spatial)
  k_qkv<<<NWIN, 512, 0, stream>>>(xn, wt4, q_b, k_b, v_b, hp, Qb, Kb, Vsoa, Vsp);
  k_attn<<<NWIN * 6, 256, 0, stream>>>(Qb, Kb, Vsoa, biasTab, attn_out);
  k_dw<<<NPIX / 256, 256, 0, stream>>>(Vsp, dw_w, dw_b, conv_out);
  // proj GEMM: input tile = attn_out(SoA) + conv_out(spatial), identity
  // epilogue, spatial output.
  k_proj<<<NWIN, 512, 0, stream>>>(attn_out, conv_out, wt4 + 3 * 36864, proj_b,
                                   x, w1v, w2v, (float*)d_out);
}

// Round 4
// 1606.811 us; speedup vs baseline: 1.3523x; 1.3523x over previous
//
#include <hip/hip_runtime.h>
#include <math.h>

#define Bn 2
#define Cn 192
#define Hn 256
#define Wn 256
#define HWn 65536
#define NPIX 25165824   /* 2*192*256*256 */
#define NROW 98304      /* 2*192*256 */
#define NWIN 2048       /* B * 32 * 32 windows */
#define PI_F 3.14159265358979323846f
#define GR2 8           /* gaussian tap radius (sigma_s ~ 1.59 px; taps>8 < 2e-6) */
#define GT 17           /* 2*GR2+1 taps */
#define TSX 88          /* xs LDS stride (mult of 4 for b128) */
#define TSS 65          /* tr/ti LDS stride (odd -> conflict-free col reads) */

// G mask in unshifted frequency coords: g1d((k+128)%256), separable.
__device__ __forceinline__ float gauss1d(int k) {
  int idx = (k + 128) & 255;
  float t = -128.0f + (float)idx * (256.0f / 255.0f);
  return expf(-(t * t) * (1.0f / 1310.72f));   // 2*cutoff^2 = 2*25.6^2
}

__global__ __launch_bounds__(256) void k_zero(float* p, int n) {
  int i = blockIdx.x * 256 + threadIdx.x;
  if (i < n) p[i] = 0.f;
}

// K_ga: spatial kernel ga[d] = ifft256(g1d)[d] by direct DFT.
// Exact integer phase reduction: angle = 2*pi*((k*d) mod 256)/256.
__global__ __launch_bounds__(256) void k_ga(float2* __restrict__ ga) {
  const int d = threadIdx.x;
  float sr = 0.f, si = 0.f;
  for (int k = 0; k < 256; ++k) {
    float g = gauss1d(k);
    int ph = (k * d) & 255;
    float a = (float)ph * (2.0f * PI_F / 256.0f);
    sr = fmaf(g, cosf(a), sr);
    si = fmaf(g, sinf(a), si);
  }
  ga[d] = make_float2(sr * (1.0f / 256.0f), si * (1.0f / 256.0f));
}

// K_gblur: fused separable circular gaussian blur (complex taps) computing
// lp_c per 32x64 tile entirely in LDS -> hp = |x - lp_c|, ca stats on |lp_c|.
// x is read once (+halo); NO global intermediate (kills round-2's L3 bottleneck).
__global__ __launch_bounds__(256) void k_gblur(const float* __restrict__ x,
                                               const float2* __restrict__ ga,
                                               float* __restrict__ hp,
                                               float* __restrict__ ca_sum,
                                               float* __restrict__ ca_max) {
  __shared__ float xs[48][TSX];        // rows y0-8..y0+39, cols x0-8..x0+71
  __shared__ float tr[48][TSS], ti[48][TSS];
  __shared__ float rsum[4], rmax[4];
  const int blk = blockIdx.x;          // plane*32 + tile
  const int plane = blk >> 5;          // b*Cn + c, < 384
  const int tile = blk & 31;           // 8 row-tiles x 4 col-tiles
  const int tyi = tile >> 2, txi = tile & 3;
  const int y0 = tyi << 5, x0 = txi << 6;
  const int t = threadIdx.x;
  // taps in registers: gc[k] = ga[(GR2-k) & 255], shared by row & col pass
  float2 gc[GT];
  #pragma unroll
  for (int k = 0; k < GT; ++k) gc[k] = ga[(GR2 - k) & 255];
  const size_t pbase = (size_t)plane << 16;
  // ---- stage xs: 48 rows x 20 float4 (circular wrap) ----
  #pragma unroll
  for (int it = 0; it < 4; ++it) {
    int u4 = t + (it << 8);
    if (u4 < 960) {
      int r = u4 / 20, cg = u4 - r * 20;
      int gy = (y0 - GR2 + r) & 255;
      int gx = (x0 - GR2 + (cg << 2)) & 255;
      float4 v = *(const float4*)&x[pbase + ((size_t)gy << 8) + gx];
      *(float4*)&xs[r][cg << 2] = v;
    }
  }
  __syncthreads();
  // ---- row pass: 48 rows x 64 cols -> tr/ti. 4 cols per thread-task. ----
  #pragma unroll
  for (int it = 0; it < 3; ++it) {
    int task = t + (it << 8);           // < 768
    int r = task >> 4, c0 = (task & 15) << 2;
    float w[20];
    #pragma unroll
    for (int q = 0; q < 5; ++q) {
      float4 v = *(const float4*)&xs[r][c0 + (q << 2)];
      w[4 * q] = v.x; w[4 * q + 1] = v.y; w[4 * q + 2] = v.z; w[4 * q + 3] = v.w;
    }
    #pragma unroll
    for (int j = 0; j < 4; ++j) {
      float sr = 0.f, si = 0.f;
      #pragma unroll
      for (int k = 0; k < GT; ++k) {
        float xv = w[j + k];
        sr = fmaf(xv, gc[k].x, sr);
        si = fmaf(xv, gc[k].y, si);
      }
      tr[r][c0 + j] = sr; ti[r][c0 + j] = si;
    }
  }
  __syncthreads();
  // ---- col pass (complex*complex) + hp + stats. 4-row groups/thread. ----
  float lsum = 0.f, lmax = 0.f;
  #pragma unroll
  for (int jt = 0; jt < 2; ++jt) {
    int task = t + (jt << 8);           // < 512
    int xc = task & 63, yl0 = (task >> 6) << 2;
    float lr[4] = {0.f, 0.f, 0.f, 0.f}, li[4] = {0.f, 0.f, 0.f, 0.f};
    #pragma unroll
    for (int o = 0; o < 20; ++o) {
      float a = tr[yl0 + o][xc], b = ti[yl0 + o][xc];
      #pragma unroll
      for (int j = 0; j < 4; ++j) {
        int k = o - j;
        if (k >= 0 && k < GT) {
          lr[j] = fmaf(a, gc[k].x, fmaf(-b, gc[k].y, lr[j]));
          li[j] = fmaf(a, gc[k].y, fmaf(b, gc[k].x, li[j]));
        }
      }
    }
    #pragma unroll
    for (int j = 0; j < 4; ++j) {
      int yl = yl0 + j;
      float xv = xs[yl + GR2][xc + GR2];
      float lp = sqrtf(lr[j] * lr[j] + li[j] * li[j]);
      float hre = xv - lr[j];
      hp[pbase + (size_t)((y0 + yl) << 8) + x0 + xc] =
          sqrtf(hre * hre + li[j] * li[j]);
      lsum += lp; lmax = fmaxf(lmax, lp);
    }
  }
  #pragma unroll
  for (int off = 32; off > 0; off >>= 1) {
    lsum += __shfl_down(lsum, off);
    lmax = fmaxf(lmax, __shfl_down(lmax, off));
  }
  if ((t & 63) == 0) { rsum[t >> 6] = lsum; rmax[t >> 6] = lmax; }
  __syncthreads();
  if (t == 0) {
    float s = rsum[0] + rsum[1] + rsum[2] + rsum[3];
    float m = fmaxf(fmaxf(rmax[0], rmax[1]), fmaxf(rmax[2], rmax[3]));
    atomicAdd(&ca_sum[plane], s);
    atomicMax((int*)&ca_max[plane], __float_as_int(m));
  }
}

// K5: sm[b,0/1,y,x] = mean/max over channels of hp
__global__ __launch_bounds__(256) void k_sm(const float* __restrict__ hp,
                                            float* __restrict__ sm) {
  int p = blockIdx.x * 256 + threadIdx.x;
  int b = p >> 16, s = p & 65535;
  const float* hpb = hp + (size_t)b * Cn * HWn + s;
  float sum = 0.f, mx = 0.f;
  for (int c = 0; c < Cn; ++c) {
    float v = hpb[(size_t)c * HWn];
    sum += v; mx = fmaxf(mx, v);
  }
  sm[(size_t)(b * 2 + 0) * HWn + s] = sum * (1.0f / 192.0f);
  sm[(size_t)(b * 2 + 1) * HWn + s] = mx;
}

// K6: channel attention MLP -> w1[b,c]
__global__ __launch_bounds__(256) void k_chatt(const float* __restrict__ ca_sum,
                                               const float* __restrict__ ca_max,
                                               const float* __restrict__ w1m,
                                               const float* __restrict__ w2m,
                                               float* __restrict__ w1out) {
  __shared__ float hid2[2][2][12];
  int tid = threadIdx.x;
  if (tid < 48) {
    int b = tid / 24, rem = tid % 24, pool = rem / 12, j = rem % 12;
    const float* src = pool ? ca_max : ca_sum;
    float scale = pool ? 1.0f : (1.0f / 65536.0f);
    float acc = 0.f;
    for (int c = 0; c < Cn; ++c) acc += src[b * Cn + c] * scale * w1m[j * Cn + c];
    hid2[b][pool][j] = fmaxf(acc, 0.f);
  }
  __syncthreads();
  for (int u = tid; u < 2 * Cn; u += 256) {
    int b = u / Cn, c = u % Cn;
    float acc = 0.f;
    #pragma unroll
    for (int j = 0; j < 12; ++j)
      acc += (hid2[b][0][j] + hid2[b][1][j]) * w2m[c * 12 + j];
    w1out[b * Cn + c] = 1.0f / (1.0f + expf(-acc));
  }
}

// K7: spatial attention -> w2[b,y,x]
__global__ __launch_bounds__(256) void k_spatt(const float* __restrict__ sm,
                                               const float* __restrict__ w3,
                                               const float* __restrict__ w5,
                                               const float* __restrict__ w7,
                                               float* __restrict__ w2out) {
  int p = blockIdx.x * 256 + threadIdx.x;
  int b = p >> 16, s = p & 65535;
  int y = s >> 8, x = s & 255;
  float acc = 0.f;
  for (int ic = 0; ic < 2; ++ic) {
    const float* in = sm + (size_t)(b * 2 + ic) * HWn;
    for (int dy = -3; dy <= 3; ++dy) {
      int yy = y + dy; if (yy < 0 || yy > 255) continue;
      for (int dx = -3; dx <= 3; ++dx) {
        int xx = x + dx; if (xx < 0 || xx > 255) continue;
        float v = in[yy * 256 + xx];
        acc += v * w7[ic * 49 + (dy + 3) * 7 + (dx + 3)];
        if (dy >= -2 && dy <= 2 && dx >= -2 && dx <= 2)
          acc += v * w5[ic * 25 + (dy + 2) * 5 + (dx + 2)];
        if (dy >= -1 && dy <= 1 && dx >= -1 && dx <= 1)
          acc += v * w3[ic * 9 + (dy + 1) * 3 + (dx + 1)];
      }
    }
  }
  w2out[p] = 1.0f / (1.0f + expf(-acc));
}

// K8: per-window LayerNorm: x*w1*w2 -> LN over channels -> xn in window-SoA
// layout: xn[w][c][n], w = global window id, n = intra-window pixel (8x8).
__global__ __launch_bounds__(256) void k_ln_w(const float* __restrict__ x,
                                              const float* __restrict__ w1v,
                                              const float* __restrict__ w2v,
                                              const float* __restrict__ lnw,
                                              const float* __restrict__ lnb,
                                              float* __restrict__ xn) {
  __shared__ float xs[Cn][64];
  __shared__ float ps[4][64], pq[4][64], mu[64], inv[64];
  const int blk = blockIdx.x;            // < 2048
  const int b = blk >> 10, wi = blk & 1023;
  const int wy = wi >> 5, wx = wi & 31;
  const int t = threadIdx.x;
  #pragma unroll
  for (int r = 0; r < 12; ++r) {
    int u4 = t + (r << 8);               // < 3072 float4s
    int f = u4 << 2;
    int c = f >> 6, n0 = f & 63;
    int y = (wy << 3) + (n0 >> 3), xx = (wx << 3) + (n0 & 7);
    const float4 xv = *(const float4*)&x[(((size_t)(b * Cn + c)) << 16) + y * 256 + xx];
    const float4 wv = *(const float4*)&w2v[((size_t)b << 16) + y * 256 + xx];
    float w1c = w1v[b * Cn + c];
    float4 v;
    v.x = xv.x * w1c * wv.x; v.y = xv.y * w1c * wv.y;
    v.z = xv.z * w1c * wv.z; v.w = xv.w * w1c * wv.w;
    *(float4*)&xs[c][n0] = v;
  }
  __syncthreads();
  {
    int n = t & 63, part = t >> 6;
    float s = 0.f, ss = 0.f;
    #pragma unroll
    for (int cc = 0; cc < 48; ++cc) {
      float v = xs[part * 48 + cc][n];
      s += v; ss += v * v;
    }
    ps[part][n] = s; pq[part][n] = ss;
  }
  __syncthreads();
  if (t < 64) {
    float s = ps[0][t] + ps[1][t] + ps[2][t] + ps[3][t];
    float q = pq[0][t] + pq[1][t] + pq[2][t] + pq[3][t];
    float m = s * (1.0f / 192.0f);
    float var = q * (1.0f / 192.0f) - m * m;
    mu[t] = m; inv[t] = rsqrtf(var + 1e-5f);
  }
  __syncthreads();
  float* outp = xn + (size_t)blk * 12288;
  #pragma unroll
  for (int r = 0; r < 12; ++r) {
    int u4 = t + (r << 8);
    int f = u4 << 2;
    int c = f >> 6, n0 = f & 63;
    float4 v = *(float4*)&xs[c][n0];
    float lw = lnw[c], lb = lnb[c];
    float4 o;
    o.x = (v.x - mu[n0 + 0]) * inv[n0 + 0] * lw + lb;
    o.y = (v.y - mu[n0 + 1]) * inv[n0 + 1] * lw + lb;
    o.z = (v.z - mu[n0 + 2]) * inv[n0 + 2] * lw + lb;
    o.w = (v.w - mu[n0 + 3]) * inv[n0 + 3] * lw + lb;
    *(float4*)&outp[f] = o;
  }
}

// K_bias: rel-pos MLP bias table [NH][64][64]
__global__ __launch_bounds__(256) void k_bias(const float* __restrict__ mw1,
                                              const float* __restrict__ mb1,
                                              const float* __restrict__ mw2,
                                              const float* __restrict__ mb2,
                                              float* __restrict__ biasTab) {
  int pair = blockIdx.x * 256 + threadIdx.x;
  int n = pair >> 6, m = pair & 63;
  float dr = (float)((n >> 3) - (m >> 3));
  float dc = (float)((n & 7) - (m & 7));
  float r0 = copysignf(log1pf(fabsf(dr)), dr);
  float r1 = copysignf(log1pf(fabsf(dc)), dc);
  float acc[6];
  #pragma unroll
  for (int h = 0; h < 6; ++h) acc[h] = mb2[h];
  for (int j = 0; j < 256; ++j) {
    float hv = fmaxf(r0 * mw1[j * 2] + r1 * mw1[j * 2 + 1] + mb1[j], 0.f);
    #pragma unroll
    for (int h = 0; h < 6; ++h) acc[h] += hv * mw2[h * 256 + j];
  }
  #pragma unroll
  for (int h = 0; h < 6; ++h) biasTab[h * 4096 + n * 64 + m] = acc[h];
}

// K_wt: transpose the 4 1x1-conv weight matrices to k-major Wt[c][o]
// so a wave's per-k weight slab (24 contiguous o) is one scalar-load run.
__global__ __launch_bounds__(256) void k_wt(const float* __restrict__ qw,
                                            const float* __restrict__ kw,
                                            const float* __restrict__ vw,
                                            const float* __restrict__ pw,
                                            float* __restrict__ wt) {
  int i = blockIdx.x * 256 + threadIdx.x;     // < 4*36864
  int m = i / 36864, r = i - m * 36864;
  int o = r / 192, c = r - o * 192;
  const float* s = (m == 0) ? qw : (m == 1) ? kw : (m == 2) ? vw : pw;
  wt[m * 36864 + c * 192 + o] = s[o * 192 + c];
}

// Core fp32 GEMM micro-loop: wave-uniform weight slab (24 out-ch, k-major,
// scalar-load path via readfirstlane-uniform o0), per-lane pixel from LDS.
// LDS traffic: ONE ds_read_b32 per k per wave vs 48 VALU cyc -> VALU-bound.
__device__ __forceinline__ void gemm24(const float* __restrict__ xsp,
                                       const float* __restrict__ wp,
                                       const float* __restrict__ bias,
                                       int o0, int lane, float acc[24]) {
  #pragma unroll
  for (int i = 0; i < 24; ++i) acc[i] = bias[o0 + i];
  #pragma unroll 2
  for (int k = 0; k < 192; ++k) {
    float xv = xsp[(k << 6) + lane];
    const float4* wr = (const float4*)(wp + k * 192 + o0);   // uniform addr
    #pragma unroll
    for (int j = 0; j < 6; ++j) {
      float4 w4 = wr[j];
      acc[4 * j + 0] = fmaf(w4.x, xv, acc[4 * j + 0]);
      acc[4 * j + 1] = fmaf(w4.y, xv, acc[4 * j + 1]);
      acc[4 * j + 2] = fmaf(w4.z, xv, acc[4 * j + 2]);
      acc[4 * j + 3] = fmaf(w4.w, xv, acc[4 * j + 3]);
    }
  }
}

// K9: fused Q/K/V 1x1-conv GEMMs. One block per window, 512 thr = 8 waves.
// X tile (48KB) staged in LDS once; three k-loops against it.
// wave wv owns out-ch [wv*24, wv*24+24); lane owns one of the 64 pixels.
// Q adds hp (prompt, spatial); V dual-writes SoA + spatial.
// hp / Vsp alias (same buffer): each address is read (Q epi) then written
// (V epi) by the SAME thread -> no __restrict__ on those two, order is safe.
// Vsoa aliases input xn: full tile staged in LDS before any store.
__global__ __launch_bounds__(512) void k_qkv(const float* __restrict__ xn,
                                             const float* __restrict__ wt,
                                             const float* __restrict__ qb,
                                             const float* __restrict__ kb,
                                             const float* __restrict__ vb,
                                             const float* hp,
                                             float* Qo, float* Ko,
                                             float* Vsoa, float* Vsp) {
  __shared__ float xs[12288];
  const int w = blockIdx.x;
  const int b = w >> 10, wi = w & 1023;
  const int wy = wi >> 5, wx = wi & 31;
  const int t = threadIdx.x;
  const float4* src = (const float4*)(xn + (size_t)w * 12288);
  #pragma unroll
  for (int r = 0; r < 6; ++r) {
    int u4 = t + (r << 9);
    ((float4*)xs)[u4] = src[u4];
  }
  __syncthreads();
  const int lane = t & 63;
  const int wv = __builtin_amdgcn_readfirstlane(t >> 6);
  const int o0 = wv * 24;
  const int y = (wy << 3) + (lane >> 3), xxp = (wx << 3) + (lane & 7);
  const int sOff = y * 256 + xxp;
  const size_t soa = (size_t)w * 12288 + (size_t)o0 * 64 + lane;
  const size_t sp = (((size_t)(b * Cn + o0)) << 16) + sOff;
  float acc[24];
  // ---- Q = conv1x1 + prompt(hp) ----
  gemm24(xs, wt, qb, o0, lane, acc);
  #pragma unroll
  for (int i = 0; i < 24; ++i)
    Qo[soa + (size_t)(i << 6)] = acc[i] + hp[sp + ((size_t)i << 16)];
  // ---- K ----
  gemm24(xs, wt + 36864, kb, o0, lane, acc);
  #pragma unroll
  for (int i = 0; i < 24; ++i)
    Ko[soa + (size_t)(i << 6)] = acc[i];
  // ---- V (SoA + spatial) ----
  gemm24(xs, wt + 2 * 36864, vb, o0, lane, acc);
  #pragma unroll
  for (int i = 0; i < 24; ++i) {
    Vsoa[soa + (size_t)(i << 6)] = acc[i];
    Vsp[sp + ((size_t)i << 16)] = acc[i];
  }
}

// K12: proj GEMM. Input tile = attn_out(SoA) + conv_out(spatial) staged in
// LDS; identity epilogue (+ x*w1*w2); spatial output.
__global__ __launch_bounds__(512) void k_proj(const float* __restrict__ attn,
                                              const float* __restrict__ conv,
                                              const float* __restrict__ wtp,
                                              const float* __restrict__ pb,
                                              const float* __restrict__ resx,
                                              const float* __restrict__ rw1,
                                              const float* __restrict__ rw2,
                                              float* __restrict__ out) {
  __shared__ float xs[12288];
  const int w = blockIdx.x;
  const int b = w >> 10, wi = w & 1023;
  const int wy = wi >> 5, wx = wi & 31;
  const int t = threadIdx.x;
  const float4* av = (const float4*)(attn + (size_t)w * 12288);
  #pragma unroll
  for (int r = 0; r < 6; ++r) {
    int u4 = t + (r << 9);
    int f = u4 << 2;
    int c = f >> 6, n0 = f & 63;
    int yy = (wy << 3) + (n0 >> 3), xx = (wx << 3) + (n0 & 7);
    float4 a = av[u4];
    float4 cv = *(const float4*)&conv[(((size_t)(b * Cn + c)) << 16) + yy * 256 + xx];
    a.x += cv.x; a.y += cv.y; a.z += cv.z; a.w += cv.w;
    ((float4*)xs)[u4] = a;
  }
  __syncthreads();
  const int lane = t & 63;
  const int wv = __builtin_amdgcn_readfirstlane(t >> 6);
  const int o0 = wv * 24;
  const int y = (wy << 3) + (lane >> 3), xxp = (wx << 3) + (lane & 7);
  const int sOff = y * 256 + xxp;
  float acc[24];
  gemm24(xs, wtp, pb, o0, lane, acc);
  const float w2s = rw2[((size_t)b << 16) + sOff];
  const size_t sp = (((size_t)(b * Cn + o0)) << 16) + sOff;
  #pragma unroll
  for (int i = 0; i < 24; ++i) {
    float idv = resx[sp + ((size_t)i << 16)] * rw1[b * Cn + o0 + i] * w2s;
    out[sp + ((size_t)i << 16)] = acc[i] + idv;
  }
}

// K10: window attention, one block per (window, head). All tensors window-SoA.
// out may alias V (block fully stages q/k/v in LDS before storing).
__global__ __launch_bounds__(256) void k_attn(const float* Q,
                                              const float* Kt,
                                              const float* V,
                                              const float* __restrict__ biasTab,
                                              float* out) {
  __shared__ float qt[64][36];     // [n][d], padded
  __shared__ float kt[64][36];     // [m][d]
  __shared__ float vl[2048];       // [d][m] flat
  __shared__ float pb[64][65];     // bias tile then softmax probs [n][m]
  const int blk = blockIdx.x;      // < 2048*6
  const int h = blk % 6, w = blk / 6;
  const int t = threadIdx.x;
  const size_t base = ((size_t)w * Cn + h * 32) * 64;
  const float4* Qg = (const float4*)(Q + base);
  const float4* Kg = (const float4*)(Kt + base);
  const float4* Vg = (const float4*)(V + base);
  #pragma unroll
  for (int r = 0; r < 2; ++r) {
    int i4 = t + (r << 8);          // < 512
    int f = i4 << 2;
    int d = f >> 6, n = f & 63;
    float4 q4 = Qg[i4], k4 = Kg[i4], v4 = Vg[i4];
    qt[n + 0][d] = q4.x * 0.17677669529663687f;
    qt[n + 1][d] = q4.y * 0.17677669529663687f;
    qt[n + 2][d] = q4.z * 0.17677669529663687f;
    qt[n + 3][d] = q4.w * 0.17677669529663687f;
    kt[n + 0][d] = k4.x; kt[n + 1][d] = k4.y;
    kt[n + 2][d] = k4.z; kt[n + 3][d] = k4.w;
    ((float4*)vl)[i4] = v4;
  }
  const float4* Bg = (const float4*)(biasTab + h * 4096);
  #pragma unroll
  for (int r = 0; r < 4; ++r) {
    int i4 = t + (r << 8);          // < 1024
    int f = i4 << 2;
    int n = f >> 6, m = f & 63;
    float4 b4 = Bg[i4];
    pb[n][m + 0] = b4.x; pb[n][m + 1] = b4.y;
    pb[n][m + 2] = b4.z; pb[n][m + 3] = b4.w;
  }
  __syncthreads();
  // ---- QK^T + bias: thread (n = t>>2, 16 m's = (t&3)*16+j) ----
  const int n = t >> 2, m0 = (t & 3) << 4;
  float sc[16];
  #pragma unroll
  for (int j = 0; j < 16; ++j) sc[j] = pb[n][m0 + j];
  #pragma unroll
  for (int d4 = 0; d4 < 32; d4 += 4) {
    float4 qv = *(const float4*)&qt[n][d4];
    #pragma unroll
    for (int j = 0; j < 16; ++j) {
      float4 kv = *(const float4*)&kt[m0 + j][d4];
      sc[j] += qv.x * kv.x + qv.y * kv.y + qv.z * kv.z + qv.w * kv.w;
    }
  }
  // ---- softmax across the 4 lanes sharing row n ----
  float mx = sc[0];
  #pragma unroll
  for (int j = 1; j < 16; ++j) mx = fmaxf(mx, sc[j]);
  mx = fmaxf(mx, __shfl_xor(mx, 1));
  mx = fmaxf(mx, __shfl_xor(mx, 2));
  float ssum = 0.f;
  #pragma unroll
  for (int j = 0; j < 16; ++j) { sc[j] = __expf(sc[j] - mx); ssum += sc[j]; }
  ssum += __shfl_xor(ssum, 1);
  ssum += __shfl_xor(ssum, 2);
  float sinv = 1.0f / ssum;
  #pragma unroll
  for (int j = 0; j < 16; ++j) sc[j] *= sinv;
  __syncthreads();   // all bias reads done before overwrite
  #pragma unroll
  for (int j = 0; j < 16; ++j) pb[n][m0 + j] = sc[j];
  __syncthreads();
  // ---- PV: thread (nn = t&63, 8 d's = (t>>6)*8..) ----
  const int nn = t & 63, dp = (t >> 6) << 3;
  float o[8];
  #pragma unroll
  for (int dd = 0; dd < 8; ++dd) o[dd] = 0.f;
  #pragma unroll
  for (int mc = 0; mc < 16; ++mc) {
    int m = mc << 2;
    float p0 = pb[nn][m], p1 = pb[nn][m + 1], p2 = pb[nn][m + 2], p3 = pb[nn][m + 3];
    #pragma unroll
    for (int dd = 0; dd < 8; ++dd) {
      float4 vv = *(const float4*)&vl[((dp + dd) << 6) + m];
      o[dd] += p0 * vv.x + p1 * vv.y + p2 * vv.z + p3 * vv.w;
    }
  }
  #pragma unroll
  for (int dd = 0; dd < 8; ++dd)
    out[base + (size_t)(dp + dd) * 64 + nn] = o[dd];
}

// K11: depthwise 5x5 reflect conv on spatial V -> conv_out (spatial)
__global__ __launch_bounds__(256) void k_dw(const float* __restrict__ V,
                                            const float* __restrict__ dww,
                                            const float* __restrict__ dwb,
                                            float* __restrict__ co) {
  size_t idx = (size_t)blockIdx.x * 256 + threadIdx.x;
  int s = (int)(idx & 65535);
  int bc = (int)(idx >> 16);
  int c = bc % Cn;
  int y = s >> 8, x = s & 255;
  const float* vb = V + ((size_t)bc << 16);
  float acc = dwb[c];
  #pragma unroll
  for (int dy = -2; dy <= 2; ++dy) {
    int yy = y + dy;
    yy = yy < 0 ? -yy : (yy > 255 ? 510 - yy : yy);
    #pragma unroll
    for (int dx = -2; dx <= 2; ++dx) {
      int xx = x + dx;
      xx = xx < 0 ? -xx : (xx > 255 ? 510 - xx : xx);
      acc += vb[yy * 256 + xx] * dww[c * 25 + (dy + 2) * 5 + (dx + 2)];
    }
  }
  co[idx] = acc;
}

extern "C" void kernel_launch(void* const* d_in, const int* in_sizes, int n_in,
                              void* d_out, int out_size, void* d_ws, size_t ws_size,
                              hipStream_t stream) {
  const float* x      = (const float*)d_in[0];
  const float* ln_w   = (const float*)d_in[1];
  const float* ln_b   = (const float*)d_in[2];
  const float* ca_w1  = (const float*)d_in[3];
  const float* ca_w2  = (const float*)d_in[4];
  const float* sa_w3  = (const float*)d_in[5];
  const float* sa_w5  = (const float*)d_in[6];
  const float* sa_w7  = (const float*)d_in[7];
  const float* q_w    = (const float*)d_in[8];
  const float* q_b    = (const float*)d_in[9];
  const float* k_w    = (const float*)d_in[10];
  const float* k_b    = (const float*)d_in[11];
  const float* v_w    = (const float*)d_in[12];
  const float* v_b    = (const float*)d_in[13];
  const float* proj_w = (const float*)d_in[14];
  const float* proj_b = (const float*)d_in[15];
  const float* meta_w1 = (const float*)d_in[16];
  const float* meta_b1 = (const float*)d_in[17];
  const float* meta_w2 = (const float*)d_in[18];
  const float* meta_b2 = (const float*)d_in[19];
  const float* dw_w   = (const float*)d_in[20];
  const float* dw_b   = (const float*)d_in[21];

  float* ws = (float*)d_ws;
  const size_t N = (size_t)NPIX;
  // Overlay (peak 3N + small):
  //  buf0: xn(SoA) -> V-SoA (in-place) -> attn_out (in-place)
  //  buf1: K(SoA)  -> conv_out (spatial)
  //  buf2: hp (spatial) -> V-spatial (per-window thread-local RAW, safe)
  //  d_out: Q(SoA) -> final output (spatial)
  float* buf0 = ws;
  float* buf1 = ws + N;
  float* buf2 = ws + 2 * N;
  float* smallb = ws + 3 * N;
  float* ca_sum  = smallb;
  float* ca_max  = smallb + 384;
  float* w1v     = smallb + 768;
  float* smb     = smallb + 1152;
  float* w2v     = smb + 262144;
  float* biasTab = w2v + 131072;
  float* wt4     = biasTab + 24576;   // 4 * 192*192 transposed weights
  float* gaBuf   = wt4 + 147456;      // 256 complex spatial gaussian taps

  float* hp = buf2;
  float* xn = buf0;
  float* Kb = buf1;
  float* Qb = (float*)d_out;
  float* Vsoa = buf0;
  float* Vsp  = buf2;
  float* attn_out = buf0;
  float* conv_out = buf1;

  k_zero<<<3, 256, 0, stream>>>(ca_sum, 768);
  k_ga<<<1, 256, 0, stream>>>((float2*)gaBuf);
  // fused separable gaussian blur -> hp + ca stats (x read once, all in LDS)
  k_gblur<<<384 * 32, 256, 0, stream>>>(x, (const float2*)gaBuf, hp, ca_sum, ca_max);
  k_sm<<<Bn * HWn / 256, 256, 0, stream>>>(hp, smb);
  k_chatt<<<1, 256, 0, stream>>>(ca_sum, ca_max, ca_w1, ca_w2, w1v);
  k_spatt<<<Bn * HWn / 256, 256, 0, stream>>>(smb, sa_w3, sa_w5, sa_w7, w2v);
  k_ln_w<<<NWIN, 256, 0, stream>>>(x, w1v, w2v, ln_w, ln_b, xn);
  k_bias<<<16, 256, 0, stream>>>(meta_w1, meta_b1, meta_w2, meta_b2, biasTab);
  k_wt<<<576, 256, 0, stream>>>(q_w, k_w, v_w, proj_w, wt4);
  // fused Q/K/V: Q(+hp)->d_out, K->buf1, V->buf0(in-place)+buf2(spatial)
  k_qkv<<<NWIN, 512, 0, stream>>>(xn, wt4, q_b, k_b, v_b, hp, Qb, Kb, Vsoa, Vsp);
  k_attn<<<NWIN * 6, 256, 0, stream>>>(Qb, Kb, Vsoa, biasTab, attn_out);
  k_dw<<<NPIX / 256, 256, 0, stream>>>(Vsp, dw_w, dw_b, conv_out);
  // proj GEMM: input tile = attn_out(SoA) + conv_out(spatial), identity
  // epilogue, spatial output.
  k_proj<<<NWIN, 512, 0, stream>>>(attn_out, conv_out, wt4 + 3 * 36864, proj_b,
                                   x, w1v, w2v, (float*)d_out);
}

// Round 7
// 1555.342 us; speedup vs baseline: 1.3971x; 1.0331x over previous
//
#include <hip/hip_runtime.h>
#include <math.h>

#define Bn 2
#define Cn 192
#define Hn 256
#define Wn 256
#define HWn 65536
#define NPIX 25165824   /* 2*192*256*256 */
#define NROW 98304      /* 2*192*256 */
#define NWIN 2048       /* B * 32 * 32 windows */
#define PI_F 3.14159265358979323846f
#define GR2 8           /* gaussian tap radius (sigma_s ~ 1.59 px; taps>8 < 2e-6) */
#define GT 17           /* 2*GR2+1 taps */
#define TSX 88          /* xs LDS stride (mult of 4 for b128) */
#define TSS 65          /* tr/ti LDS stride (odd -> conflict-free col reads) */

// G mask in unshifted frequency coords: g1d((k+128)%256), separable.
__device__ __forceinline__ float gauss1d(int k) {
  int idx = (k + 128) & 255;
  float t = -128.0f + (float)idx * (256.0f / 255.0f);
  return expf(-(t * t) * (1.0f / 1310.72f));   // 2*cutoff^2 = 2*25.6^2
}

__global__ __launch_bounds__(256) void k_zero(float* p, int n) {
  int i = blockIdx.x * 256 + threadIdx.x;
  if (i < n) p[i] = 0.f;
}

// K_ga: spatial kernel ga[d] = ifft256(g1d)[d] by direct DFT.
// Exact integer phase reduction: angle = 2*pi*((k*d) mod 256)/256.
__global__ __launch_bounds__(256) void k_ga(float2* __restrict__ ga) {
  const int d = threadIdx.x;
  float sr = 0.f, si = 0.f;
  for (int k = 0; k < 256; ++k) {
    float g = gauss1d(k);
    int ph = (k * d) & 255;
    float a = (float)ph * (2.0f * PI_F / 256.0f);
    sr = fmaf(g, cosf(a), sr);
    si = fmaf(g, sinf(a), si);
  }
  ga[d] = make_float2(sr * (1.0f / 256.0f), si * (1.0f / 256.0f));
}

// K_gblur: fused separable circular gaussian blur (complex taps) computing
// lp_c per 32x64 tile entirely in LDS -> hp = |x - lp_c|, ca stats on |lp_c|.
// x is read once (+halo); NO global intermediate.
__global__ __launch_bounds__(256) void k_gblur(const float* __restrict__ x,
                                               const float2* __restrict__ ga,
                                               float* __restrict__ hp,
                                               float* __restrict__ ca_sum,
                                               float* __restrict__ ca_max) {
  __shared__ float xs[48][TSX];        // rows y0-8..y0+39, cols x0-8..x0+71
  __shared__ float tr[48][TSS], ti[48][TSS];
  __shared__ float rsum[4], rmax[4];
  const int blk = blockIdx.x;          // plane*32 + tile
  const int plane = blk >> 5;          // b*Cn + c, < 384
  const int tile = blk & 31;           // 8 row-tiles x 4 col-tiles
  const int tyi = tile >> 2, txi = tile & 3;
  const int y0 = tyi << 5, x0 = txi << 6;
  const int t = threadIdx.x;
  // taps in registers: gc[k] = ga[(GR2-k) & 255], shared by row & col pass
  float2 gc[GT];
  #pragma unroll
  for (int k = 0; k < GT; ++k) gc[k] = ga[(GR2 - k) & 255];
  const size_t pbase = (size_t)plane << 16;
  // ---- stage xs: 48 rows x 20 float4 (circular wrap) ----
  #pragma unroll
  for (int it = 0; it < 4; ++it) {
    int u4 = t + (it << 8);
    if (u4 < 960) {
      int r = u4 / 20, cg = u4 - r * 20;
      int gy = (y0 - GR2 + r) & 255;
      int gx = (x0 - GR2 + (cg << 2)) & 255;
      float4 v = *(const float4*)&x[pbase + ((size_t)gy << 8) + gx];
      *(float4*)&xs[r][cg << 2] = v;
    }
  }
  __syncthreads();
  // ---- row pass: 48 rows x 64 cols -> tr/ti. 4 cols per thread-task. ----
  #pragma unroll
  for (int it = 0; it < 3; ++it) {
    int task = t + (it << 8);           // < 768
    int r = task >> 4, c0 = (task & 15) << 2;
    float w[20];
    #pragma unroll
    for (int q = 0; q < 5; ++q) {
      float4 v = *(const float4*)&xs[r][c0 + (q << 2)];
      w[4 * q] = v.x; w[4 * q + 1] = v.y; w[4 * q + 2] = v.z; w[4 * q + 3] = v.w;
    }
    #pragma unroll
    for (int j = 0; j < 4; ++j) {
      float sr = 0.f, si = 0.f;
      #pragma unroll
      for (int k = 0; k < GT; ++k) {
        float xv = w[j + k];
        sr = fmaf(xv, gc[k].x, sr);
        si = fmaf(xv, gc[k].y, si);
      }
      tr[r][c0 + j] = sr; ti[r][c0 + j] = si;
    }
  }
  __syncthreads();
  // ---- col pass (complex*complex) + hp + stats. 4-row groups/thread. ----
  float lsum = 0.f, lmax = 0.f;
  #pragma unroll
  for (int jt = 0; jt < 2; ++jt) {
    int task = t + (jt << 8);           // < 512
    int xc = task & 63, yl0 = (task >> 6) << 2;
    float lr[4] = {0.f, 0.f, 0.f, 0.f}, li[4] = {0.f, 0.f, 0.f, 0.f};
    #pragma unroll
    for (int o = 0; o < 20; ++o) {
      float a = tr[yl0 + o][xc], b = ti[yl0 + o][xc];
      #pragma unroll
      for (int j = 0; j < 4; ++j) {
        int k = o - j;
        if (k >= 0 && k < GT) {
          lr[j] = fmaf(a, gc[k].x, fmaf(-b, gc[k].y, lr[j]));
          li[j] = fmaf(a, gc[k].y, fmaf(b, gc[k].x, li[j]));
        }
      }
    }
    #pragma unroll
    for (int j = 0; j < 4; ++j) {
      int yl = yl0 + j;
      float xv = xs[yl + GR2][xc + GR2];
      float lp = sqrtf(lr[j] * lr[j] + li[j] * li[j]);
      float hre = xv - lr[j];
      hp[pbase + (size_t)((y0 + yl) << 8) + x0 + xc] =
          sqrtf(hre * hre + li[j] * li[j]);
      lsum += lp; lmax = fmaxf(lmax, lp);
    }
  }
  #pragma unroll
  for (int off = 32; off > 0; off >>= 1) {
    lsum += __shfl_down(lsum, off);
    lmax = fmaxf(lmax, __shfl_down(lmax, off));
  }
  if ((t & 63) == 0) { rsum[t >> 6] = lsum; rmax[t >> 6] = lmax; }
  __syncthreads();
  if (t == 0) {
    float s = rsum[0] + rsum[1] + rsum[2] + rsum[3];
    float m = fmaxf(fmaxf(rmax[0], rmax[1]), fmaxf(rmax[2], rmax[3]));
    atomicAdd(&ca_sum[plane], s);
    atomicMax((int*)&ca_max[plane], __float_as_int(m));
  }
}

// K5: sm[b,0/1,y,x] = mean/max over channels of hp
__global__ __launch_bounds__(256) void k_sm(const float* __restrict__ hp,
                                            float* __restrict__ sm) {
  int p = blockIdx.x * 256 + threadIdx.x;
  int b = p >> 16, s = p & 65535;
  const float* hpb = hp + (size_t)b * Cn * HWn + s;
  float sum = 0.f, mx = 0.f;
  for (int c = 0; c < Cn; ++c) {
    float v = hpb[(size_t)c * HWn];
    sum += v; mx = fmaxf(mx, v);
  }
  sm[(size_t)(b * 2 + 0) * HWn + s] = sum * (1.0f / 192.0f);
  sm[(size_t)(b * 2 + 1) * HWn + s] = mx;
}

// K6: channel attention MLP -> w1[b,c]
__global__ __launch_bounds__(256) void k_chatt(const float* __restrict__ ca_sum,
                                               const float* __restrict__ ca_max,
                                               const float* __restrict__ w1m,
                                               const float* __restrict__ w2m,
                                               float* __restrict__ w1out) {
  __shared__ float hid2[2][2][12];
  int tid = threadIdx.x;
  if (tid < 48) {
    int b = tid / 24, rem = tid % 24, pool = rem / 12, j = rem % 12;
    const float* src = pool ? ca_max : ca_sum;
    float scale = pool ? 1.0f : (1.0f / 65536.0f);
    float acc = 0.f;
    for (int c = 0; c < Cn; ++c) acc += src[b * Cn + c] * scale * w1m[j * Cn + c];
    hid2[b][pool][j] = fmaxf(acc, 0.f);
  }
  __syncthreads();
  for (int u = tid; u < 2 * Cn; u += 256) {
    int b = u / Cn, c = u % Cn;
    float acc = 0.f;
    #pragma unroll
    for (int j = 0; j < 12; ++j)
      acc += (hid2[b][0][j] + hid2[b][1][j]) * w2m[c * 12 + j];
    w1out[b * Cn + c] = 1.0f / (1.0f + expf(-acc));
  }
}

// K7: spatial attention -> w2[b,y,x]
__global__ __launch_bounds__(256) void k_spatt(const float* __restrict__ sm,
                                               const float* __restrict__ w3,
                                               const float* __restrict__ w5,
                                               const float* __restrict__ w7,
                                               float* __restrict__ w2out) {
  int p = blockIdx.x * 256 + threadIdx.x;
  int b = p >> 16, s = p & 65535;
  int y = s >> 8, x = s & 255;
  float acc = 0.f;
  for (int ic = 0; ic < 2; ++ic) {
    const float* in = sm + (size_t)(b * 2 + ic) * HWn;
    for (int dy = -3; dy <= 3; ++dy) {
      int yy = y + dy; if (yy < 0 || yy > 255) continue;
      for (int dx = -3; dx <= 3; ++dx) {
        int xx = x + dx; if (xx < 0 || xx > 255) continue;
        float v = in[yy * 256 + xx];
        acc += v * w7[ic * 49 + (dy + 3) * 7 + (dx + 3)];
        if (dy >= -2 && dy <= 2 && dx >= -2 && dx <= 2)
          acc += v * w5[ic * 25 + (dy + 2) * 5 + (dx + 2)];
        if (dy >= -1 && dy <= 1 && dx >= -1 && dx <= 1)
          acc += v * w3[ic * 9 + (dy + 1) * 3 + (dx + 1)];
      }
    }
  }
  w2out[p] = 1.0f / (1.0f + expf(-acc));
}

// K_bias: rel-pos MLP bias table [NH][64][64]
__global__ __launch_bounds__(256) void k_bias(const float* __restrict__ mw1,
                                              const float* __restrict__ mb1,
                                              const float* __restrict__ mw2,
                                              const float* __restrict__ mb2,
                                              float* __restrict__ biasTab) {
  int pair = blockIdx.x * 256 + threadIdx.x;
  int n = pair >> 6, m = pair & 63;
  float dr = (float)((n >> 3) - (m >> 3));
  float dc = (float)((n & 7) - (m & 7));
  float r0 = copysignf(log1pf(fabsf(dr)), dr);
  float r1 = copysignf(log1pf(fabsf(dc)), dc);
  float acc[6];
  #pragma unroll
  for (int h = 0; h < 6; ++h) acc[h] = mb2[h];
  for (int j = 0; j < 256; ++j) {
    float hv = fmaxf(r0 * mw1[j * 2] + r1 * mw1[j * 2 + 1] + mb1[j], 0.f);
    #pragma unroll
    for (int h = 0; h < 6; ++h) acc[h] += hv * mw2[h * 256 + j];
  }
  #pragma unroll
  for (int h = 0; h < 6; ++h) biasTab[h * 4096 + n * 64 + m] = acc[h];
}

// K_wt: transpose the 4 1x1-conv weight matrices to k-major Wt[c][o]
// so a wave's per-k weight slab (24 contiguous o) is one scalar-load run.
__global__ __launch_bounds__(256) void k_wt(const float* __restrict__ qw,
                                            const float* __restrict__ kw,
                                            const float* __restrict__ vw,
                                            const float* __restrict__ pw,
                                            float* __restrict__ wt) {
  int i = blockIdx.x * 256 + threadIdx.x;     // < 4*36864
  int m = i / 36864, r = i - m * 36864;
  int o = r / 192, c = r - o * 192;
  const float* s = (m == 0) ? qw : (m == 1) ? kw : (m == 2) ? vw : pw;
  wt[m * 36864 + c * 192 + o] = s[o * 192 + c];
}

// Core fp32 GEMM micro-loop: wave-uniform weight slab (24 out-ch, k-major,
// scalar-load path via readfirstlane-uniform o0), per-lane pixel from LDS.
// unroll 2: R1-validated codegen (40 VGPR measured).
__device__ __forceinline__ void gemm24(const float* __restrict__ xsp,
                                       const float* __restrict__ wp,
                                       const float* __restrict__ bias,
                                       int o0, int lane, float acc[24]) {
  #pragma unroll
  for (int i = 0; i < 24; ++i) acc[i] = bias[o0 + i];
  #pragma unroll 2
  for (int k = 0; k < 192; ++k) {
    float xv = xsp[(k << 6) + lane];
    const float4* wr = (const float4*)(wp + k * 192 + o0);   // uniform addr
    #pragma unroll
    for (int j = 0; j < 6; ++j) {
      float4 w4 = wr[j];
      acc[4 * j + 0] = fmaf(w4.x, xv, acc[4 * j + 0]);
      acc[4 * j + 1] = fmaf(w4.y, xv, acc[4 * j + 1]);
      acc[4 * j + 2] = fmaf(w4.z, xv, acc[4 * j + 2]);
      acc[4 * j + 3] = fmaf(w4.w, xv, acc[4 * j + 3]);
    }
  }
}

// K9: fused LN + Q/K/V 1x1-conv GEMMs. One block per window, 512 thr = 8 waves.
// Staging gathers x*w1*w2 from spatial x, LayerNorms in LDS (replaces the
// former k_ln_w kernel + its 200 MB HBM round-trip), then three k-loops.
// wave wv owns out-ch [wv*24, wv*24+24); lane owns one of the 64 pixels.
// Q adds hp (prompt, spatial); V dual-writes SoA + spatial.
// hp / Vsp alias (same buffer): each address is read (Q epi) then written
// (V epi) by the SAME thread -> no __restrict__ on those two, order is safe.
__global__ __launch_bounds__(512) void k_qkv(const float* __restrict__ x,
                                             const float* __restrict__ w1v,
                                             const float* __restrict__ w2v,
                                             const float* __restrict__ lnw,
                                             const float* __restrict__ lnb,
                                             const float* __restrict__ wt,
                                             const float* __restrict__ qb,
                                             const float* __restrict__ kb,
                                             const float* __restrict__ vb,
                                             const float* hp,
                                             float* Qo, float* Ko,
                                             float* Vsoa, float* Vsp) {
  __shared__ float xs[Cn][64];
  __shared__ float ps[8][64], pq[8][64], mu[64], inv[64];
  const int w = blockIdx.x;
  const int b = w >> 10, wi = w & 1023;
  const int wy = wi >> 5, wx = wi & 31;
  const int t = threadIdx.x;
  // ---- stage x*w1*w2 into xs[c][n] ----
  #pragma unroll
  for (int r = 0; r < 6; ++r) {
    int u4 = t + (r << 9);               // < 3072 float4s
    int f = u4 << 2;
    int c = f >> 6, n0 = f & 63;
    int y = (wy << 3) + (n0 >> 3), xx = (wx << 3) + (n0 & 7);
    const float4 xv = *(const float4*)&x[(((size_t)(b * Cn + c)) << 16) + y * 256 + xx];
    const float4 wv = *(const float4*)&w2v[((size_t)b << 16) + y * 256 + xx];
    float w1c = w1v[b * Cn + c];
    float4 v;
    v.x = xv.x * w1c * wv.x; v.y = xv.y * w1c * wv.y;
    v.z = xv.z * w1c * wv.z; v.w = xv.w * w1c * wv.w;
    *(float4*)&xs[c][n0] = v;
  }
  __syncthreads();
  // ---- LN reduction: 8 partials x 24 channels per pixel ----
  {
    int n = t & 63, part = t >> 6;
    float s = 0.f, ss = 0.f;
    #pragma unroll
    for (int cc = 0; cc < 24; ++cc) {
      float v = xs[part * 24 + cc][n];
      s += v; ss += v * v;
    }
    ps[part][n] = s; pq[part][n] = ss;
  }
  __syncthreads();
  if (t < 64) {
    float s = 0.f, q = 0.f;
    #pragma unroll
    for (int p = 0; p < 8; ++p) { s += ps[p][t]; q += pq[p][t]; }
    float m = s * (1.0f / 192.0f);
    float var = q * (1.0f / 192.0f) - m * m;
    mu[t] = m; inv[t] = rsqrtf(var + 1e-5f);
  }
  __syncthreads();
  // ---- normalize in place ----
  #pragma unroll
  for (int r = 0; r < 6; ++r) {
    int u4 = t + (r << 9);
    int f = u4 << 2;
    int c = f >> 6, n0 = f & 63;
    float4 v = *(float4*)&xs[c][n0];
    float lw = lnw[c], lb = lnb[c];
    float4 o;
    o.x = (v.x - mu[n0 + 0]) * inv[n0 + 0] * lw + lb;
    o.y = (v.y - mu[n0 + 1]) * inv[n0 + 1] * lw + lb;
    o.z = (v.z - mu[n0 + 2]) * inv[n0 + 2] * lw + lb;
    o.w = (v.w - mu[n0 + 3]) * inv[n0 + 3] * lw + lb;
    *(float4*)&xs[c][n0] = o;
  }
  __syncthreads();
  // ---- GEMMs ----
  const int lane = t & 63;
  const int wv = __builtin_amdgcn_readfirstlane(t >> 6);
  const int o0 = wv * 24;
  const int y = (wy << 3) + (lane >> 3), xxp = (wx << 3) + (lane & 7);
  const int sOff = y * 256 + xxp;
  const size_t soa = (size_t)w * 12288 + (size_t)o0 * 64 + lane;
  const size_t sp = (((size_t)(b * Cn + o0)) << 16) + sOff;
  float acc[24];
  // ---- Q = conv1x1 + prompt(hp) ----
  gemm24(&xs[0][0], wt, qb, o0, lane, acc);
  #pragma unroll
  for (int i = 0; i < 24; ++i)
    Qo[soa + (size_t)(i << 6)] = acc[i] + hp[sp + ((size_t)i << 16)];
  // ---- K ----
  gemm24(&xs[0][0], wt + 36864, kb, o0, lane, acc);
  #pragma unroll
  for (int i = 0; i < 24; ++i)
    Ko[soa + (size_t)(i << 6)] = acc[i];
  // ---- V (SoA + spatial) ----
  gemm24(&xs[0][0], wt + 2 * 36864, vb, o0, lane, acc);
  #pragma unroll
  for (int i = 0; i < 24; ++i) {
    Vsoa[soa + (size_t)(i << 6)] = acc[i];
    Vsp[sp + ((size_t)i << 16)] = acc[i];
  }
}

// K12: proj GEMM. Input tile = attn_out(SoA) + conv_out(spatial) staged in
// LDS; identity epilogue (+ x*w1*w2); spatial output.
__global__ __launch_bounds__(512) void k_proj(const float* __restrict__ attn,
                                              const float* __restrict__ conv,
                                              const float* __restrict__ wtp,
                                              const float* __restrict__ pb,
                                              const float* __restrict__ resx,
                                              const float* __restrict__ rw1,
                                              const float* __restrict__ rw2,
                                              float* __restrict__ out) {
  __shared__ float xs[Cn][64];
  const int w = blockIdx.x;
  const int b = w >> 10, wi = w & 1023;
  const int wy = wi >> 5, wx = wi & 31;
  const int t = threadIdx.x;
  const float4* av = (const float4*)(attn + (size_t)w * 12288);
  #pragma unroll
  for (int r = 0; r < 6; ++r) {
    int u4 = t + (r << 9);
    int f = u4 << 2;
    int c = f >> 6, n0 = f & 63;
    int yy = (wy << 3) + (n0 >> 3), xx = (wx << 3) + (n0 & 7);
    float4 a = av[u4];
    float4 cv = *(const float4*)&conv[(((size_t)(b * Cn + c)) << 16) + yy * 256 + xx];
    a.x += cv.x; a.y += cv.y; a.z += cv.z; a.w += cv.w;
    *(float4*)&xs[c][n0] = a;
  }
  __syncthreads();
  const int lane = t & 63;
  const int wv = __builtin_amdgcn_readfirstlane(t >> 6);
  const int o0 = wv * 24;
  const int y = (wy << 3) + (lane >> 3), xxp = (wx << 3) + (lane & 7);
  const int sOff = y * 256 + xxp;
  float acc[24];
  gemm24(&xs[0][0], wtp, pb, o0, lane, acc);
  const float w2s = rw2[((size_t)b << 16) + sOff];
  const size_t sp = (((size_t)(b * Cn + o0)) << 16) + sOff;
  #pragma unroll
  for (int i = 0; i < 24; ++i) {
    float idv = resx[sp + ((size_t)i << 16)] * rw1[b * Cn + o0 + i] * w2s;
    out[sp + ((size_t)i << 16)] = acc[i] + idv;
  }
}

// K10: window attention, one block per (window, head). All tensors window-SoA.
// out may alias V (block fully stages q/k/v in LDS before storing).
__global__ __launch_bounds__(256) void k_attn(const float* Q,
                                              const float* Kt,
                                              const float* V,
                                              const float* __restrict__ biasTab,
                                              float* out) {
  __shared__ float qt[64][36];     // [n][d], padded
  __shared__ float kt[64][36];     // [m][d]
  __shared__ float vl[2048];       // [d][m] flat
  __shared__ float pb[64][65];     // bias tile then softmax probs [n][m]
  const int blk = blockIdx.x;      // < 2048*6
  const int h = blk % 6, w = blk / 6;
  const int t = threadIdx.x;
  const size_t base = ((size_t)w * Cn + h * 32) * 64;
  const float4* Qg = (const float4*)(Q + base);
  const float4* Kg = (const float4*)(Kt + base);
  const float4* Vg = (const float4*)(V + base);
  #pragma unroll
  for (int r = 0; r < 2; ++r) {
    int i4 = t + (r << 8);          // < 512
    int f = i4 << 2;
    int d = f >> 6, n = f & 63;
    float4 q4 = Qg[i4], k4 = Kg[i4], v4 = Vg[i4];
    qt[n + 0][d] = q4.x * 0.17677669529663687f;
    qt[n + 1][d] = q4.y * 0.17677669529663687f;
    qt[n + 2][d] = q4.z * 0.17677669529663687f;
    qt[n + 3][d] = q4.w * 0.17677669529663687f;
    kt[n + 0][d] = k4.x; kt[n + 1][d] = k4.y;
    kt[n + 2][d] = k4.z; kt[n + 3][d] = k4.w;
    ((float4*)vl)[i4] = v4;
  }
  const float4* Bg = (const float4*)(biasTab + h * 4096);
  #pragma unroll
  for (int r = 0; r < 4; ++r) {
    int i4 = t + (r << 8);          // < 1024
    int f = i4 << 2;
    int n = f >> 6, m = f & 63;
    float4 b4 = Bg[i4];
    pb[n][m + 0] = b4.x; pb[n][m + 1] = b4.y;
    pb[n][m + 2] = b4.z; pb[n][m + 3] = b4.w;
  }
  __syncthreads();
  // ---- QK^T + bias: thread (n = t>>2, 16 m's = (t&3)*16+j) ----
  const int n = t >> 2, m0 = (t & 3) << 4;
  float sc[16];
  #pragma unroll
  for (int j = 0; j < 16; ++j) sc[j] = pb[n][m0 + j];
  #pragma unroll
  for (int d4 = 0; d4 < 32; d4 += 4) {
    float4 qv = *(const float4*)&qt[n][d4];
    #pragma unroll
    for (int j = 0; j < 16; ++j) {
      float4 kv = *(const float4*)&kt[m0 + j][d4];
      sc[j] += qv.x * kv.x + qv.y * kv.y + qv.z * kv.z + qv.w * kv.w;
    }
  }
  // ---- softmax across the 4 lanes sharing row n ----
  float mx = sc[0];
  #pragma unroll
  for (int j = 1; j < 16; ++j) mx = fmaxf(mx, sc[j]);
  mx = fmaxf(mx, __shfl_xor(mx, 1));
  mx = fmaxf(mx, __shfl_xor(mx, 2));
  float ssum = 0.f;
  #pragma unroll
  for (int j = 0; j < 16; ++j) { sc[j] = __expf(sc[j] - mx); ssum += sc[j]; }
  ssum += __shfl_xor(ssum, 1);
  ssum += __shfl_xor(ssum, 2);
  float sinv = 1.0f / ssum;
  #pragma unroll
  for (int j = 0; j < 16; ++j) sc[j] *= sinv;
  __syncthreads();   // all bias reads done before overwrite
  #pragma unroll
  for (int j = 0; j < 16; ++j) pb[n][m0 + j] = sc[j];
  __syncthreads();
  // ---- PV: thread (nn = t&63, 8 d's = (t>>6)*8..) ----
  const int nn = t & 63, dp = (t >> 6) << 3;
  float o[8];
  #pragma unroll
  for (int dd = 0; dd < 8; ++dd) o[dd] = 0.f;
  #pragma unroll
  for (int mc = 0; mc < 16; ++mc) {
    int m = mc << 2;
    float p0 = pb[nn][m], p1 = pb[nn][m + 1], p2 = pb[nn][m + 2], p3 = pb[nn][m + 3];
    #pragma unroll
    for (int dd = 0; dd < 8; ++dd) {
      float4 vv = *(const float4*)&vl[((dp + dd) << 6) + m];
      o[dd] += p0 * vv.x + p1 * vv.y + p2 * vv.z + p3 * vv.w;
    }
  }
  #pragma unroll
  for (int dd = 0; dd < 8; ++dd)
    out[base + (size_t)(dp + dd) * 64 + nn] = o[dd];
}

// K11: depthwise 5x5 reflect conv on spatial V -> conv_out (spatial)
__global__ __launch_bounds__(256) void k_dw(const float* __restrict__ V,
                                            const float* __restrict__ dww,
                                            const float* __restrict__ dwb,
                                            float* __restrict__ co) {
  size_t idx = (size_t)blockIdx.x * 256 + threadIdx.x;
  int s = (int)(idx & 65535);
  int bc = (int)(idx >> 16);
  int c = bc % Cn;
  int y = s >> 8, x = s & 255;
  const float* vb = V + ((size_t)bc << 16);
  float acc = dwb[c];
  #pragma unroll
  for (int dy = -2; dy <= 2; ++dy) {
    int yy = y + dy;
    yy = yy < 0 ? -yy : (yy > 255 ? 510 - yy : yy);
    #pragma unroll
    for (int dx = -2; dx <= 2; ++dx) {
      int xx = x + dx;
      xx = xx < 0 ? -xx : (xx > 255 ? 510 - xx : xx);
      acc += vb[yy * 256 + xx] * dww[c * 25 + (dy + 2) * 5 + (dx + 2)];
    }
  }
  co[idx] = acc;
}

extern "C" void kernel_launch(void* const* d_in, const int* in_sizes, int n_in,
                              void* d_out, int out_size, void* d_ws, size_t ws_size,
                              hipStream_t stream) {
  const float* x      = (const float*)d_in[0];
  const float* ln_w   = (const float*)d_in[1];
  const float* ln_b   = (const float*)d_in[2];
  const float* ca_w1  = (const float*)d_in[3];
  const float* ca_w2  = (const float*)d_in[4];
  const float* sa_w3  = (const float*)d_in[5];
  const float* sa_w5  = (const float*)d_in[6];
  const float* sa_w7  = (const float*)d_in[7];
  const float* q_w    = (const float*)d_in[8];
  const float* q_b    = (const float*)d_in[9];
  const float* k_w    = (const float*)d_in[10];
  const float* k_b    = (const float*)d_in[11];
  const float* v_w    = (const float*)d_in[12];
  const float* v_b    = (const float*)d_in[13];
  const float* proj_w = (const float*)d_in[14];
  const float* proj_b = (const float*)d_in[15];
  const float* meta_w1 = (const float*)d_in[16];
  const float* meta_b1 = (const float*)d_in[17];
  const float* meta_w2 = (const float*)d_in[18];
  const float* meta_b2 = (const float*)d_in[19];
  const float* dw_w   = (const float*)d_in[20];
  const float* dw_b   = (const float*)d_in[21];

  float* ws = (float*)d_ws;
  const size_t N = (size_t)NPIX;
  // Overlay (peak 3N + small):
  //  buf0: V-SoA -> attn_out (in-place)
  //  buf1: K(SoA) -> conv_out (spatial)
  //  buf2: hp (spatial) -> V-spatial (per-window thread-local RAW, safe)
  //  d_out: Q(SoA) -> final output (spatial)
  float* buf0 = ws;
  float* buf1 = ws + N;
  float* buf2 = ws + 2 * N;
  float* smallb = ws + 3 * N;
  float* ca_sum  = smallb;
  float* ca_max  = smallb + 384;
  float* w1v     = smallb + 768;
  float* smb     = smallb + 1152;
  float* w2v     = smb + 262144;
  float* biasTab = w2v + 131072;
  float* wt4     = biasTab + 24576;   // 4 * 192*192 transposed weights
  float* gaBuf   = wt4 + 147456;      // 256 complex spatial gaussian taps

  float* hp = buf2;
  float* Kb = buf1;
  float* Qb = (float*)d_out;
  float* Vsoa = buf0;
  float* Vsp  = buf2;
  float* attn_out = buf0;
  float* conv_out = buf1;

  k_zero<<<3, 256, 0, stream>>>(ca_sum, 768);
  k_ga<<<1, 256, 0, stream>>>((float2*)gaBuf);
  // fused separable gaussian blur -> hp + ca stats (x read once, all in LDS)
  k_gblur<<<384 * 32, 256, 0, stream>>>(x, (const float2*)gaBuf, hp, ca_sum, ca_max);
  k_sm<<<Bn * HWn / 256, 256, 0, stream>>>(hp, smb);
  k_chatt<<<1, 256, 0, stream>>>(ca_sum, ca_max, ca_w1, ca_w2, w1v);
  k_spatt<<<Bn * HWn / 256, 256, 0, stream>>>(smb, sa_w3, sa_w5, sa_w7, w2v);
  k_bias<<<16, 256, 0, stream>>>(meta_w1, meta_b1, meta_w2, meta_b2, biasTab);
  k_wt<<<576, 256, 0, stream>>>(q_w, k_w, v_w, proj_w, wt4);
  // fused LN + Q/K/V: Q(+hp)->d_out, K->buf1, V->buf0+buf2(spatial)
  k_qkv<<<NWIN, 512, 0, stream>>>(x, w1v, w2v, ln_w, ln_b, wt4, q_b, k_b, v_b,
                                  hp, Qb, Kb, Vsoa, Vsp);
  k_attn<<<NWIN * 6, 256, 0, stream>>>(Qb, Kb, Vsoa, biasTab, attn_out);
  k_dw<<<NPIX / 256, 256, 0, stream>>>(Vsp, dw_w, dw_b, conv_out);
  // proj GEMM: input tile = attn_out(SoA) + conv_out(spatial), identity
  // epilogue, spatial output.
  k_proj<<<NWIN, 512, 0, stream>>>(attn_out, conv_out, wt4 + 3 * 36864, proj_b,
                                   x, w1v, w2v, (float*)d_out);
}

// Round 8
// 1437.349 us; speedup vs baseline: 1.5118x; 1.0821x over previous
//
#include <hip/hip_runtime.h>
#include <math.h>

#define Bn 2
#define Cn 192
#define Hn 256
#define Wn 256
#define HWn 65536
#define NPIX 25165824   /* 2*192*256*256 */
#define NROW 98304      /* 2*192*256 */
#define NWIN 2048       /* B * 32 * 32 windows */
#define PI_F 3.14159265358979323846f
#define GR2 8           /* gaussian tap radius (sigma_s ~ 1.59 px; taps>8 < 2e-6) */
#define GT 17           /* 2*GR2+1 taps */
#define TSX 88          /* xs LDS stride (mult of 4 for b128) */
#define TSS 65          /* tr/ti LDS stride (odd -> conflict-free col reads) */

// XCD-aware bijective block swizzle: consecutive logical ids land on the SAME
// XCD (dispatch round-robins raw blockIdx across 8 XCDs) -> adjacent windows
// share L2 cache lines. nwg must be divisible by 8 (all our grids are).
__device__ __forceinline__ int xswz(int bid, int nwg) {
  return (bid & 7) * (nwg >> 3) + (bid >> 3);
}

// G mask in unshifted frequency coords: g1d((k+128)%256), separable.
__device__ __forceinline__ float gauss1d(int k) {
  int idx = (k + 128) & 255;
  float t = -128.0f + (float)idx * (256.0f / 255.0f);
  return expf(-(t * t) * (1.0f / 1310.72f));   // 2*cutoff^2 = 2*25.6^2
}

__global__ __launch_bounds__(256) void k_zero(float* p, int n) {
  int i = blockIdx.x * 256 + threadIdx.x;
  if (i < n) p[i] = 0.f;
}

// K_ga: spatial kernel ga[d] = ifft256(g1d)[d] by direct DFT.
// Exact integer phase reduction: angle = 2*pi*((k*d) mod 256)/256.
__global__ __launch_bounds__(256) void k_ga(float2* __restrict__ ga) {
  const int d = threadIdx.x;
  float sr = 0.f, si = 0.f;
  for (int k = 0; k < 256; ++k) {
    float g = gauss1d(k);
    int ph = (k * d) & 255;
    float a = (float)ph * (2.0f * PI_F / 256.0f);
    sr = fmaf(g, cosf(a), sr);
    si = fmaf(g, sinf(a), si);
  }
  ga[d] = make_float2(sr * (1.0f / 256.0f), si * (1.0f / 256.0f));
}

// K_gblur: fused separable circular gaussian blur (complex taps) computing
// lp_c per 32x64 tile entirely in LDS -> hp = |x - lp_c|, ca stats on |lp_c|.
// x is read once (+halo); NO global intermediate.
__global__ __launch_bounds__(256) void k_gblur(const float* __restrict__ x,
                                               const float2* __restrict__ ga,
                                               float* __restrict__ hp,
                                               float* __restrict__ ca_sum,
                                               float* __restrict__ ca_max) {
  __shared__ float xs[48][TSX];        // rows y0-8..y0+39, cols x0-8..x0+71
  __shared__ float tr[48][TSS], ti[48][TSS];
  __shared__ float rsum[4], rmax[4];
  const int blk = xswz(blockIdx.x, 384 * 32);  // plane*32 + tile
  const int plane = blk >> 5;          // b*Cn + c, < 384
  const int tile = blk & 31;           // 8 row-tiles x 4 col-tiles
  const int tyi = tile >> 2, txi = tile & 3;
  const int y0 = tyi << 5, x0 = txi << 6;
  const int t = threadIdx.x;
  // taps in registers: gc[k] = ga[(GR2-k) & 255], shared by row & col pass
  float2 gc[GT];
  #pragma unroll
  for (int k = 0; k < GT; ++k) gc[k] = ga[(GR2 - k) & 255];
  const size_t pbase = (size_t)plane << 16;
  // ---- stage xs: 48 rows x 20 float4 (circular wrap) ----
  #pragma unroll
  for (int it = 0; it < 4; ++it) {
    int u4 = t + (it << 8);
    if (u4 < 960) {
      int r = u4 / 20, cg = u4 - r * 20;
      int gy = (y0 - GR2 + r) & 255;
      int gx = (x0 - GR2 + (cg << 2)) & 255;
      float4 v = *(const float4*)&x[pbase + ((size_t)gy << 8) + gx];
      *(float4*)&xs[r][cg << 2] = v;
    }
  }
  __syncthreads();
  // ---- row pass: 48 rows x 64 cols -> tr/ti. 4 cols per thread-task. ----
  #pragma unroll
  for (int it = 0; it < 3; ++it) {
    int task = t + (it << 8);           // < 768
    int r = task >> 4, c0 = (task & 15) << 2;
    float w[20];
    #pragma unroll
    for (int q = 0; q < 5; ++q) {
      float4 v = *(const float4*)&xs[r][c0 + (q << 2)];
      w[4 * q] = v.x; w[4 * q + 1] = v.y; w[4 * q + 2] = v.z; w[4 * q + 3] = v.w;
    }
    #pragma unroll
    for (int j = 0; j < 4; ++j) {
      float sr = 0.f, si = 0.f;
      #pragma unroll
      for (int k = 0; k < GT; ++k) {
        float xv = w[j + k];
        sr = fmaf(xv, gc[k].x, sr);
        si = fmaf(xv, gc[k].y, si);
      }
      tr[r][c0 + j] = sr; ti[r][c0 + j] = si;
    }
  }
  __syncthreads();
  // ---- col pass (complex*complex) + hp + stats. 4-row groups/thread. ----
  float lsum = 0.f, lmax = 0.f;
  #pragma unroll
  for (int jt = 0; jt < 2; ++jt) {
    int task = t + (jt << 8);           // < 512
    int xc = task & 63, yl0 = (task >> 6) << 2;
    float lr[4] = {0.f, 0.f, 0.f, 0.f}, li[4] = {0.f, 0.f, 0.f, 0.f};
    #pragma unroll
    for (int o = 0; o < 20; ++o) {
      float a = tr[yl0 + o][xc], b = ti[yl0 + o][xc];
      #pragma unroll
      for (int j = 0; j < 4; ++j) {
        int k = o - j;
        if (k >= 0 && k < GT) {
          lr[j] = fmaf(a, gc[k].x, fmaf(-b, gc[k].y, lr[j]));
          li[j] = fmaf(a, gc[k].y, fmaf(b, gc[k].x, li[j]));
        }
      }
    }
    #pragma unroll
    for (int j = 0; j < 4; ++j) {
      int yl = yl0 + j;
      float xv = xs[yl + GR2][xc + GR2];
      float lp = sqrtf(lr[j] * lr[j] + li[j] * li[j]);
      float hre = xv - lr[j];
      hp[pbase + (size_t)((y0 + yl) << 8) + x0 + xc] =
          sqrtf(hre * hre + li[j] * li[j]);
      lsum += lp; lmax = fmaxf(lmax, lp);
    }
  }
  #pragma unroll
  for (int off = 32; off > 0; off >>= 1) {
    lsum += __shfl_down(lsum, off);
    lmax = fmaxf(lmax, __shfl_down(lmax, off));
  }
  if ((t & 63) == 0) { rsum[t >> 6] = lsum; rmax[t >> 6] = lmax; }
  __syncthreads();
  if (t == 0) {
    float s = rsum[0] + rsum[1] + rsum[2] + rsum[3];
    float m = fmaxf(fmaxf(rmax[0], rmax[1]), fmaxf(rmax[2], rmax[3]));
    atomicAdd(&ca_sum[plane], s);
    atomicMax((int*)&ca_max[plane], __float_as_int(m));
  }
}

// K5: sm[b,0/1,y,x] = mean/max over channels of hp
__global__ __launch_bounds__(256) void k_sm(const float* __restrict__ hp,
                                            float* __restrict__ sm) {
  int p = blockIdx.x * 256 + threadIdx.x;
  int b = p >> 16, s = p & 65535;
  const float* hpb = hp + (size_t)b * Cn * HWn + s;
  float sum = 0.f, mx = 0.f;
  for (int c = 0; c < Cn; ++c) {
    float v = hpb[(size_t)c * HWn];
    sum += v; mx = fmaxf(mx, v);
  }
  sm[(size_t)(b * 2 + 0) * HWn + s] = sum * (1.0f / 192.0f);
  sm[(size_t)(b * 2 + 1) * HWn + s] = mx;
}

// K6: channel attention MLP -> w1[b,c]
__global__ __launch_bounds__(256) void k_chatt(const float* __restrict__ ca_sum,
                                               const float* __restrict__ ca_max,
                                               const float* __restrict__ w1m,
                                               const float* __restrict__ w2m,
                                               float* __restrict__ w1out) {
  __shared__ float hid2[2][2][12];
  int tid = threadIdx.x;
  if (tid < 48) {
    int b = tid / 24, rem = tid % 24, pool = rem / 12, j = rem % 12;
    const float* src = pool ? ca_max : ca_sum;
    float scale = pool ? 1.0f : (1.0f / 65536.0f);
    float acc = 0.f;
    for (int c = 0; c < Cn; ++c) acc += src[b * Cn + c] * scale * w1m[j * Cn + c];
    hid2[b][pool][j] = fmaxf(acc, 0.f);
  }
  __syncthreads();
  for (int u = tid; u < 2 * Cn; u += 256) {
    int b = u / Cn, c = u % Cn;
    float acc = 0.f;
    #pragma unroll
    for (int j = 0; j < 12; ++j)
      acc += (hid2[b][0][j] + hid2[b][1][j]) * w2m[c * 12 + j];
    w1out[b * Cn + c] = 1.0f / (1.0f + expf(-acc));
  }
}

// K7: spatial attention -> w2[b,y,x]
__global__ __launch_bounds__(256) void k_spatt(const float* __restrict__ sm,
                                               const float* __restrict__ w3,
                                               const float* __restrict__ w5,
                                               const float* __restrict__ w7,
                                               float* __restrict__ w2out) {
  int p = blockIdx.x * 256 + threadIdx.x;
  int b = p >> 16, s = p & 65535;
  int y = s >> 8, x = s & 255;
  float acc = 0.f;
  for (int ic = 0; ic < 2; ++ic) {
    const float* in = sm + (size_t)(b * 2 + ic) * HWn;
    for (int dy = -3; dy <= 3; ++dy) {
      int yy = y + dy; if (yy < 0 || yy > 255) continue;
      for (int dx = -3; dx <= 3; ++dx) {
        int xx = x + dx; if (xx < 0 || xx > 255) continue;
        float v = in[yy * 256 + xx];
        acc += v * w7[ic * 49 + (dy + 3) * 7 + (dx + 3)];
        if (dy >= -2 && dy <= 2 && dx >= -2 && dx <= 2)
          acc += v * w5[ic * 25 + (dy + 2) * 5 + (dx + 2)];
        if (dy >= -1 && dy <= 1 && dx >= -1 && dx <= 1)
          acc += v * w3[ic * 9 + (dy + 1) * 3 + (dx + 1)];
      }
    }
  }
  w2out[p] = 1.0f / (1.0f + expf(-acc));
}

// K_bias: rel-pos MLP bias table [NH][64][64]
__global__ __launch_bounds__(256) void k_bias(const float* __restrict__ mw1,
                                              const float* __restrict__ mb1,
                                              const float* __restrict__ mw2,
                                              const float* __restrict__ mb2,
                                              float* __restrict__ biasTab) {
  int pair = blockIdx.x * 256 + threadIdx.x;
  int n = pair >> 6, m = pair & 63;
  float dr = (float)((n >> 3) - (m >> 3));
  float dc = (float)((n & 7) - (m & 7));
  float r0 = copysignf(log1pf(fabsf(dr)), dr);
  float r1 = copysignf(log1pf(fabsf(dc)), dc);
  float acc[6];
  #pragma unroll
  for (int h = 0; h < 6; ++h) acc[h] = mb2[h];
  for (int j = 0; j < 256; ++j) {
    float hv = fmaxf(r0 * mw1[j * 2] + r1 * mw1[j * 2 + 1] + mb1[j], 0.f);
    #pragma unroll
    for (int h = 0; h < 6; ++h) acc[h] += hv * mw2[h * 256 + j];
  }
  #pragma unroll
  for (int h = 0; h < 6; ++h) biasTab[h * 4096 + n * 64 + m] = acc[h];
}

// K_wt: transpose the 4 1x1-conv weight matrices to k-major Wt[c][o]
// so a wave's per-k weight slab (24 contiguous o) is one scalar-load run.
__global__ __launch_bounds__(256) void k_wt(const float* __restrict__ qw,
                                            const float* __restrict__ kw,
                                            const float* __restrict__ vw,
                                            const float* __restrict__ pw,
                                            float* __restrict__ wt) {
  int i = blockIdx.x * 256 + threadIdx.x;     // < 4*36864
  int m = i / 36864, r = i - m * 36864;
  int o = r / 192, c = r - o * 192;
  const float* s = (m == 0) ? qw : (m == 1) ? kw : (m == 2) ? vw : pw;
  wt[m * 36864 + c * 192 + o] = s[o * 192 + c];
}

// Core fp32 GEMM micro-loop: wave-uniform weight slab (24 out-ch, k-major,
// scalar-load path via readfirstlane-uniform o0), per-lane pixel from LDS.
// unroll 2: R1-validated codegen (40 VGPR measured).
__device__ __forceinline__ void gemm24(const float* __restrict__ xsp,
                                       const float* __restrict__ wp,
                                       const float* __restrict__ bias,
                                       int o0, int lane, float acc[24]) {
  #pragma unroll
  for (int i = 0; i < 24; ++i) acc[i] = bias[o0 + i];
  #pragma unroll 2
  for (int k = 0; k < 192; ++k) {
    float xv = xsp[(k << 6) + lane];
    const float4* wr = (const float4*)(wp + k * 192 + o0);   // uniform addr
    #pragma unroll
    for (int j = 0; j < 6; ++j) {
      float4 w4 = wr[j];
      acc[4 * j + 0] = fmaf(w4.x, xv, acc[4 * j + 0]);
      acc[4 * j + 1] = fmaf(w4.y, xv, acc[4 * j + 1]);
      acc[4 * j + 2] = fmaf(w4.z, xv, acc[4 * j + 2]);
      acc[4 * j + 3] = fmaf(w4.w, xv, acc[4 * j + 3]);
    }
  }
}

// K9: fused LN + Q/K/V 1x1-conv GEMMs. One block per window, 512 thr = 8 waves.
// Staging gathers x*w1*w2 from spatial x, LayerNorms in LDS, then three
// k-loops. XCD swizzle: adjacent windows share the 128B cache lines of the
// 32B/row window gathers -> L2 hits instead of HBM re-fetch.
// hp / Vsp alias (same buffer): each address is read (Q epi) then written
// (V epi) by the SAME thread -> no __restrict__ on those two, order is safe.
__global__ __launch_bounds__(512) void k_qkv(const float* __restrict__ x,
                                             const float* __restrict__ w1v,
                                             const float* __restrict__ w2v,
                                             const float* __restrict__ lnw,
                                             const float* __restrict__ lnb,
                                             const float* __restrict__ wt,
                                             const float* __restrict__ qb,
                                             const float* __restrict__ kb,
                                             const float* __restrict__ vb,
                                             const float* hp,
                                             float* Qo, float* Ko,
                                             float* Vsoa, float* Vsp) {
  __shared__ float xs[Cn][64];
  __shared__ float ps[8][64], pq[8][64], mu[64], inv[64];
  const int w = xswz(blockIdx.x, NWIN);
  const int b = w >> 10, wi = w & 1023;
  const int wy = wi >> 5, wx = wi & 31;
  const int t = threadIdx.x;
  // ---- stage x*w1*w2 into xs[c][n] ----
  #pragma unroll
  for (int r = 0; r < 6; ++r) {
    int u4 = t + (r << 9);               // < 3072 float4s
    int f = u4 << 2;
    int c = f >> 6, n0 = f & 63;
    int y = (wy << 3) + (n0 >> 3), xx = (wx << 3) + (n0 & 7);
    const float4 xv = *(const float4*)&x[(((size_t)(b * Cn + c)) << 16) + y * 256 + xx];
    const float4 wv = *(const float4*)&w2v[((size_t)b << 16) + y * 256 + xx];
    float w1c = w1v[b * Cn + c];
    float4 v;
    v.x = xv.x * w1c * wv.x; v.y = xv.y * w1c * wv.y;
    v.z = xv.z * w1c * wv.z; v.w = xv.w * w1c * wv.w;
    *(float4*)&xs[c][n0] = v;
  }
  __syncthreads();
  // ---- LN reduction: 8 partials x 24 channels per pixel ----
  {
    int n = t & 63, part = t >> 6;
    float s = 0.f, ss = 0.f;
    #pragma unroll
    for (int cc = 0; cc < 24; ++cc) {
      float v = xs[part * 24 + cc][n];
      s += v; ss += v * v;
    }
    ps[part][n] = s; pq[part][n] = ss;
  }
  __syncthreads();
  if (t < 64) {
    float s = 0.f, q = 0.f;
    #pragma unroll
    for (int p = 0; p < 8; ++p) { s += ps[p][t]; q += pq[p][t]; }
    float m = s * (1.0f / 192.0f);
    float var = q * (1.0f / 192.0f) - m * m;
    mu[t] = m; inv[t] = rsqrtf(var + 1e-5f);
  }
  __syncthreads();
  // ---- normalize in place ----
  #pragma unroll
  for (int r = 0; r < 6; ++r) {
    int u4 = t + (r << 9);
    int f = u4 << 2;
    int c = f >> 6, n0 = f & 63;
    float4 v = *(float4*)&xs[c][n0];
    float lw = lnw[c], lb = lnb[c];
    float4 o;
    o.x = (v.x - mu[n0 + 0]) * inv[n0 + 0] * lw + lb;
    o.y = (v.y - mu[n0 + 1]) * inv[n0 + 1] * lw + lb;
    o.z = (v.z - mu[n0 + 2]) * inv[n0 + 2] * lw + lb;
    o.w = (v.w - mu[n0 + 3]) * inv[n0 + 3] * lw + lb;
    *(float4*)&xs[c][n0] = o;
  }
  __syncthreads();
  // ---- GEMMs ----
  const int lane = t & 63;
  const int wv = __builtin_amdgcn_readfirstlane(t >> 6);
  const int o0 = wv * 24;
  const int y = (wy << 3) + (lane >> 3), xxp = (wx << 3) + (lane & 7);
  const int sOff = y * 256 + xxp;
  const size_t soa = (size_t)w * 12288 + (size_t)o0 * 64 + lane;
  const size_t sp = (((size_t)(b * Cn + o0)) << 16) + sOff;
  float acc[24];
  // ---- Q = conv1x1 + prompt(hp) ----
  gemm24(&xs[0][0], wt, qb, o0, lane, acc);
  #pragma unroll
  for (int i = 0; i < 24; ++i)
    Qo[soa + (size_t)(i << 6)] = acc[i] + hp[sp + ((size_t)i << 16)];
  // ---- K ----
  gemm24(&xs[0][0], wt + 36864, kb, o0, lane, acc);
  #pragma unroll
  for (int i = 0; i < 24; ++i)
    Ko[soa + (size_t)(i << 6)] = acc[i];
  // ---- V (SoA + spatial) ----
  gemm24(&xs[0][0], wt + 2 * 36864, vb, o0, lane, acc);
  #pragma unroll
  for (int i = 0; i < 24; ++i) {
    Vsoa[soa + (size_t)(i << 6)] = acc[i];
    Vsp[sp + ((size_t)i << 16)] = acc[i];
  }
}

// K12: proj GEMM. Input tile = attn_out(SoA) + conv_out(spatial) staged in
// LDS; identity epilogue (+ x*w1*w2); spatial output. XCD swizzle for the
// spatial gathers/stores (same mechanism as k_qkv).
__global__ __launch_bounds__(512) void k_proj(const float* __restrict__ attn,
                                              const float* __restrict__ conv,
                                              const float* __restrict__ wtp,
                                              const float* __restrict__ pb,
                                              const float* __restrict__ resx,
                                              const float* __restrict__ rw1,
                                              const float* __restrict__ rw2,
                                              float* __restrict__ out) {
  __shared__ float xs[Cn][64];
  const int w = xswz(blockIdx.x, NWIN);
  const int b = w >> 10, wi = w & 1023;
  const int wy = wi >> 5, wx = wi & 31;
  const int t = threadIdx.x;
  const float4* av = (const float4*)(attn + (size_t)w * 12288);
  #pragma unroll
  for (int r = 0; r < 6; ++r) {
    int u4 = t + (r << 9);
    int f = u4 << 2;
    int c = f >> 6, n0 = f & 63;
    int yy = (wy << 3) + (n0 >> 3), xx = (wx << 3) + (n0 & 7);
    float4 a = av[u4];
    float4 cv = *(const float4*)&conv[(((size_t)(b * Cn + c)) << 16) + yy * 256 + xx];
    a.x += cv.x; a.y += cv.y; a.z += cv.z; a.w += cv.w;
    *(float4*)&xs[c][n0] = a;
  }
  __syncthreads();
  const int lane = t & 63;
  const int wv = __builtin_amdgcn_readfirstlane(t >> 6);
  const int o0 = wv * 24;
  const int y = (wy << 3) + (lane >> 3), xxp = (wx << 3) + (lane & 7);
  const int sOff = y * 256 + xxp;
  float acc[24];
  gemm24(&xs[0][0], wtp, pb, o0, lane, acc);
  const float w2s = rw2[((size_t)b << 16) + sOff];
  const size_t sp = (((size_t)(b * Cn + o0)) << 16) + sOff;
  #pragma unroll
  for (int i = 0; i < 24; ++i) {
    float idv = resx[sp + ((size_t)i << 16)] * rw1[b * Cn + o0 + i] * w2s;
    out[sp + ((size_t)i << 16)] = acc[i] + idv;
  }
}

// K10: window attention, one block per (window, head). All tensors window-SoA.
// XCD swizzle: the 6 head-blocks of one window read the SAME Q/K/V tiles —
// co-locate them on one XCD's L2. out may alias V (fully staged first).
__global__ __launch_bounds__(256) void k_attn(const float* Q,
                                              const float* Kt,
                                              const float* V,
                                              const float* __restrict__ biasTab,
                                              float* out) {
  __shared__ float qt[64][36];     // [n][d], padded
  __shared__ float kt[64][36];     // [m][d]
  __shared__ float vl[2048];       // [d][m] flat
  __shared__ float pb[64][65];     // bias tile then softmax probs [n][m]
  const int blk = xswz(blockIdx.x, NWIN * 6);  // < 2048*6
  const int h = blk % 6, w = blk / 6;
  const int t = threadIdx.x;
  const size_t base = ((size_t)w * Cn + h * 32) * 64;
  const float4* Qg = (const float4*)(Q + base);
  const float4* Kg = (const float4*)(Kt + base);
  const float4* Vg = (const float4*)(V + base);
  #pragma unroll
  for (int r = 0; r < 2; ++r) {
    int i4 = t + (r << 8);          // < 512
    int f = i4 << 2;
    int d = f >> 6, n = f & 63;
    float4 q4 = Qg[i4], k4 = Kg[i4], v4 = Vg[i4];
    qt[n + 0][d] = q4.x * 0.17677669529663687f;
    qt[n + 1][d] = q4.y * 0.17677669529663687f;
    qt[n + 2][d] = q4.z * 0.17677669529663687f;
    qt[n + 3][d] = q4.w * 0.17677669529663687f;
    kt[n + 0][d] = k4.x; kt[n + 1][d] = k4.y;
    kt[n + 2][d] = k4.z; kt[n + 3][d] = k4.w;
    ((float4*)vl)[i4] = v4;
  }
  const float4* Bg = (const float4*)(biasTab + h * 4096);
  #pragma unroll
  for (int r = 0; r < 4; ++r) {
    int i4 = t + (r << 8);          // < 1024
    int f = i4 << 2;
    int n = f >> 6, m = f & 63;
    float4 b4 = Bg[i4];
    pb[n][m + 0] = b4.x; pb[n][m + 1] = b4.y;
    pb[n][m + 2] = b4.z; pb[n][m + 3] = b4.w;
  }
  __syncthreads();
  // ---- QK^T + bias: thread (n = t>>2, 16 m's = (t&3)*16+j) ----
  const int n = t >> 2, m0 = (t & 3) << 4;
  float sc[16];
  #pragma unroll
  for (int j = 0; j < 16; ++j) sc[j] = pb[n][m0 + j];
  #pragma unroll
  for (int d4 = 0; d4 < 32; d4 += 4) {
    float4 qv = *(const float4*)&qt[n][d4];
    #pragma unroll
    for (int j = 0; j < 16; ++j) {
      float4 kv = *(const float4*)&kt[m0 + j][d4];
      sc[j] += qv.x * kv.x + qv.y * kv.y + qv.z * kv.z + qv.w * kv.w;
    }
  }
  // ---- softmax across the 4 lanes sharing row n ----
  float mx = sc[0];
  #pragma unroll
  for (int j = 1; j < 16; ++j) mx = fmaxf(mx, sc[j]);
  mx = fmaxf(mx, __shfl_xor(mx, 1));
  mx = fmaxf(mx, __shfl_xor(mx, 2));
  float ssum = 0.f;
  #pragma unroll
  for (int j = 0; j < 16; ++j) { sc[j] = __expf(sc[j] - mx); ssum += sc[j]; }
  ssum += __shfl_xor(ssum, 1);
  ssum += __shfl_xor(ssum, 2);
  float sinv = 1.0f / ssum;
  #pragma unroll
  for (int j = 0; j < 16; ++j) sc[j] *= sinv;
  __syncthreads();   // all bias reads done before overwrite
  #pragma unroll
  for (int j = 0; j < 16; ++j) pb[n][m0 + j] = sc[j];
  __syncthreads();
  // ---- PV: thread (nn = t&63, 8 d's = (t>>6)*8..) ----
  const int nn = t & 63, dp = (t >> 6) << 3;
  float o[8];
  #pragma unroll
  for (int dd = 0; dd < 8; ++dd) o[dd] = 0.f;
  #pragma unroll
  for (int mc = 0; mc < 16; ++mc) {
    int m = mc << 2;
    float p0 = pb[nn][m], p1 = pb[nn][m + 1], p2 = pb[nn][m + 2], p3 = pb[nn][m + 3];
    #pragma unroll
    for (int dd = 0; dd < 8; ++dd) {
      float4 vv = *(const float4*)&vl[((dp + dd) << 6) + m];
      o[dd] += p0 * vv.x + p1 * vv.y + p2 * vv.z + p3 * vv.w;
    }
  }
  #pragma unroll
  for (int dd = 0; dd < 8; ++dd)
    out[base + (size_t)(dp + dd) * 64 + nn] = o[dd];
}

// K11: depthwise 5x5 reflect conv on spatial V -> conv_out (spatial)
__global__ __launch_bounds__(256) void k_dw(const float* __restrict__ V,
                                            const float* __restrict__ dww,
                                            const float* __restrict__ dwb,
                                            float* __restrict__ co) {
  size_t idx = (size_t)blockIdx.x * 256 + threadIdx.x;
  int s = (int)(idx & 65535);
  int bc = (int)(idx >> 16);
  int c = bc % Cn;
  int y = s >> 8, x = s & 255;
  const float* vb = V + ((size_t)bc << 16);
  float acc = dwb[c];
  #pragma unroll
  for (int dy = -2; dy <= 2; ++dy) {
    int yy = y + dy;
    yy = yy < 0 ? -yy : (yy > 255 ? 510 - yy : yy);
    #pragma unroll
    for (int dx = -2; dx <= 2; ++dx) {
      int xx = x + dx;
      xx = xx < 0 ? -xx : (xx > 255 ? 510 - xx : xx);
      acc += vb[yy * 256 + xx] * dww[c * 25 + (dy + 2) * 5 + (dx + 2)];
    }
  }
  co[idx] = acc;
}

extern "C" void kernel_launch(void* const* d_in, const int* in_sizes, int n_in,
                              void* d_out, int out_size, void* d_ws, size_t ws_size,
                              hipStream_t stream) {
  const float* x      = (const float*)d_in[0];
  const float* ln_w   = (const float*)d_in[1];
  const float* ln_b   = (const float*)d_in[2];
  const float* ca_w1  = (const float*)d_in[3];
  const float* ca_w2  = (const float*)d_in[4];
  const float* sa_w3  = (const float*)d_in[5];
  const float* sa_w5  = (const float*)d_in[6];
  const float* sa_w7  = (const float*)d_in[7];
  const float* q_w    = (const float*)d_in[8];
  const float* q_b    = (const float*)d_in[9];
  const float* k_w    = (const float*)d_in[10];
  const float* k_b    = (const float*)d_in[11];
  const float* v_w    = (const float*)d_in[12];
  const float* v_b    = (const float*)d_in[13];
  const float* proj_w = (const float*)d_in[14];
  const float* proj_b = (const float*)d_in[15];
  const float* meta_w1 = (const float*)d_in[16];
  const float* meta_b1 = (const float*)d_in[17];
  const float* meta_w2 = (const float*)d_in[18];
  const float* meta_b2 = (const float*)d_in[19];
  const float* dw_w   = (const float*)d_in[20];
  const float* dw_b   = (const float*)d_in[21];

  float* ws = (float*)d_ws;
  const size_t N = (size_t)NPIX;
  // Overlay (peak 3N + small):
  //  buf0: V-SoA -> attn_out (in-place)
  //  buf1: K(SoA) -> conv_out (spatial)
  //  buf2: hp (spatial) -> V-spatial (per-window thread-local RAW, safe)
  //  d_out: Q(SoA) -> final output (spatial)
  float* buf0 = ws;
  float* buf1 = ws + N;
  float* buf2 = ws + 2 * N;
  float* smallb = ws + 3 * N;
  float* ca_sum  = smallb;
  float* ca_max  = smallb + 384;
  float* w1v     = smallb + 768;
  float* smb     = smallb + 1152;
  float* w2v     = smb + 262144;
  float* biasTab = w2v + 131072;
  float* wt4     = biasTab + 24576;   // 4 * 192*192 transposed weights
  float* gaBuf   = wt4 + 147456;      // 256 complex spatial gaussian taps

  float* hp = buf2;
  float* Kb = buf1;
  float* Qb = (float*)d_out;
  float* Vsoa = buf0;
  float* Vsp  = buf2;
  float* attn_out = buf0;
  float* conv_out = buf1;

  k_zero<<<3, 256, 0, stream>>>(ca_sum, 768);
  k_ga<<<1, 256, 0, stream>>>((float2*)gaBuf);
  // fused separable gaussian blur -> hp + ca stats (x read once, all in LDS)
  k_gblur<<<384 * 32, 256, 0, stream>>>(x, (const float2*)gaBuf, hp, ca_sum, ca_max);
  k_sm<<<Bn * HWn / 256, 256, 0, stream>>>(hp, smb);
  k_chatt<<<1, 256, 0, stream>>>(ca_sum, ca_max, ca_w1, ca_w2, w1v);
  k_spatt<<<Bn * HWn / 256, 256, 0, stream>>>(smb, sa_w3, sa_w5, sa_w7, w2v);
  k_bias<<<16, 256, 0, stream>>>(meta_w1, meta_b1, meta_w2, meta_b2, biasTab);
  k_wt<<<576, 256, 0, stream>>>(q_w, k_w, v_w, proj_w, wt4);
  // fused LN + Q/K/V: Q(+hp)->d_out, K->buf1, V->buf0+buf2(spatial)
  k_qkv<<<NWIN, 512, 0, stream>>>(x, w1v, w2v, ln_w, ln_b, wt4, q_b, k_b, v_b,
                                  hp, Qb, Kb, Vsoa, Vsp);
  k_attn<<<NWIN * 6, 256, 0, stream>>>(Qb, Kb, Vsoa, biasTab, attn_out);
  k_dw<<<NPIX / 256, 256, 0, stream>>>(Vsp, dw_w, dw_b, conv_out);
  // proj GEMM: input tile = attn_out(SoA) + conv_out(spatial), identity
  // epilogue, spatial output.
  k_proj<<<NWIN, 512, 0, stream>>>(attn_out, conv_out, wt4 + 3 * 36864, proj_b,
                                   x, w1v, w2v, (float*)d_out);
}

// Round 9
// 1430.163 us; speedup vs baseline: 1.5194x; 1.0050x over previous
//
#include <hip/hip_runtime.h>
#include <math.h>

#define Bn 2
#define Cn 192
#define Hn 256
#define Wn 256
#define HWn 65536
#define NPIX 25165824   /* 2*192*256*256 */
#define NROW 98304      /* 2*192*256 */
#define NWIN 2048       /* B * 32 * 32 windows */
#define PI_F 3.14159265358979323846f
#define GR2 8           /* gaussian tap radius (sigma_s ~ 1.59 px; taps>8 < 2e-6) */
#define GT 17           /* 2*GR2+1 taps */
#define TSX 88          /* xs LDS stride (mult of 4 for b128) */
#define TSS 65          /* tr/ti LDS stride (odd -> conflict-free col reads) */

// XCD-aware bijective block swizzle: consecutive logical ids land on the SAME
// XCD (dispatch round-robins raw blockIdx across 8 XCDs) -> adjacent windows
// share L2 cache lines. nwg must be divisible by 8 (all our grids are).
__device__ __forceinline__ int xswz(int bid, int nwg) {
  return (bid & 7) * (nwg >> 3) + (bid >> 3);
}

// G mask in unshifted frequency coords: g1d((k+128)%256), separable.
__device__ __forceinline__ float gauss1d(int k) {
  int idx = (k + 128) & 255;
  float t = -128.0f + (float)idx * (256.0f / 255.0f);
  return expf(-(t * t) * (1.0f / 1310.72f));   // 2*cutoff^2 = 2*25.6^2
}

__global__ __launch_bounds__(256) void k_zero(float* p, int n) {
  int i = blockIdx.x * 256 + threadIdx.x;
  if (i < n) p[i] = 0.f;
}

// K_ga: spatial kernel ga[d] = ifft256(g1d)[d] by direct DFT.
// Exact integer phase reduction: angle = 2*pi*((k*d) mod 256)/256.
__global__ __launch_bounds__(256) void k_ga(float2* __restrict__ ga) {
  const int d = threadIdx.x;
  float sr = 0.f, si = 0.f;
  for (int k = 0; k < 256; ++k) {
    float g = gauss1d(k);
    int ph = (k * d) & 255;
    float a = (float)ph * (2.0f * PI_F / 256.0f);
    sr = fmaf(g, cosf(a), sr);
    si = fmaf(g, sinf(a), si);
  }
  ga[d] = make_float2(sr * (1.0f / 256.0f), si * (1.0f / 256.0f));
}

// K_gblur: fused separable circular gaussian blur (complex taps) computing
// lp_c per 32x64 tile entirely in LDS -> hp = |x - lp_c|, ca stats on |lp_c|.
// x is read once (+halo); NO global intermediate.
__global__ __launch_bounds__(256) void k_gblur(const float* __restrict__ x,
                                               const float2* __restrict__ ga,
                                               float* __restrict__ hp,
                                               float* __restrict__ ca_sum,
                                               float* __restrict__ ca_max) {
  __shared__ float xs[48][TSX];        // rows y0-8..y0+39, cols x0-8..x0+71
  __shared__ float tr[48][TSS], ti[48][TSS];
  __shared__ float rsum[4], rmax[4];
  const int blk = xswz(blockIdx.x, 384 * 32);  // plane*32 + tile
  const int plane = blk >> 5;          // b*Cn + c, < 384
  const int tile = blk & 31;           // 8 row-tiles x 4 col-tiles
  const int tyi = tile >> 2, txi = tile & 3;
  const int y0 = tyi << 5, x0 = txi << 6;
  const int t = threadIdx.x;
  // taps in registers: gc[k] = ga[(GR2-k) & 255], shared by row & col pass
  float2 gc[GT];
  #pragma unroll
  for (int k = 0; k < GT; ++k) gc[k] = ga[(GR2 - k) & 255];
  const size_t pbase = (size_t)plane << 16;
  // ---- stage xs: 48 rows x 20 float4 (circular wrap) ----
  #pragma unroll
  for (int it = 0; it < 4; ++it) {
    int u4 = t + (it << 8);
    if (u4 < 960) {
      int r = u4 / 20, cg = u4 - r * 20;
      int gy = (y0 - GR2 + r) & 255;
      int gx = (x0 - GR2 + (cg << 2)) & 255;
      float4 v = *(const float4*)&x[pbase + ((size_t)gy << 8) + gx];
      *(float4*)&xs[r][cg << 2] = v;
    }
  }
  __syncthreads();
  // ---- row pass: 48 rows x 64 cols -> tr/ti. 4 cols per thread-task. ----
  #pragma unroll
  for (int it = 0; it < 3; ++it) {
    int task = t + (it << 8);           // < 768
    int r = task >> 4, c0 = (task & 15) << 2;
    float w[20];
    #pragma unroll
    for (int q = 0; q < 5; ++q) {
      float4 v = *(const float4*)&xs[r][c0 + (q << 2)];
      w[4 * q] = v.x; w[4 * q + 1] = v.y; w[4 * q + 2] = v.z; w[4 * q + 3] = v.w;
    }
    #pragma unroll
    for (int j = 0; j < 4; ++j) {
      float sr = 0.f, si = 0.f;
      #pragma unroll
      for (int k = 0; k < GT; ++k) {
        float xv = w[j + k];
        sr = fmaf(xv, gc[k].x, sr);
        si = fmaf(xv, gc[k].y, si);
      }
      tr[r][c0 + j] = sr; ti[r][c0 + j] = si;
    }
  }
  __syncthreads();
  // ---- col pass (complex*complex) + hp + stats. 4-row groups/thread. ----
  float lsum = 0.f, lmax = 0.f;
  #pragma unroll
  for (int jt = 0; jt < 2; ++jt) {
    int task = t + (jt << 8);           // < 512
    int xc = task & 63, yl0 = (task >> 6) << 2;
    float lr[4] = {0.f, 0.f, 0.f, 0.f}, li[4] = {0.f, 0.f, 0.f, 0.f};
    #pragma unroll
    for (int o = 0; o < 20; ++o) {
      float a = tr[yl0 + o][xc], b = ti[yl0 + o][xc];
      #pragma unroll
      for (int j = 0; j < 4; ++j) {
        int k = o - j;
        if (k >= 0 && k < GT) {
          lr[j] = fmaf(a, gc[k].x, fmaf(-b, gc[k].y, lr[j]));
          li[j] = fmaf(a, gc[k].y, fmaf(b, gc[k].x, li[j]));
        }
      }
    }
    #pragma unroll
    for (int j = 0; j < 4; ++j) {
      int yl = yl0 + j;
      float xv = xs[yl + GR2][xc + GR2];
      float lp = sqrtf(lr[j] * lr[j] + li[j] * li[j]);
      float hre = xv - lr[j];
      hp[pbase + (size_t)((y0 + yl) << 8) + x0 + xc] =
          sqrtf(hre * hre + li[j] * li[j]);
      lsum += lp; lmax = fmaxf(lmax, lp);
    }
  }
  #pragma unroll
  for (int off = 32; off > 0; off >>= 1) {
    lsum += __shfl_down(lsum, off);
    lmax = fmaxf(lmax, __shfl_down(lmax, off));
  }
  if ((t & 63) == 0) { rsum[t >> 6] = lsum; rmax[t >> 6] = lmax; }
  __syncthreads();
  if (t == 0) {
    float s = rsum[0] + rsum[1] + rsum[2] + rsum[3];
    float m = fmaxf(fmaxf(rmax[0], rmax[1]), fmaxf(rmax[2], rmax[3]));
    atomicAdd(&ca_sum[plane], s);
    atomicMax((int*)&ca_max[plane], __float_as_int(m));
  }
}

// K5: sm[b,0/1,y,x] = mean/max over channels of hp
__global__ __launch_bounds__(256) void k_sm(const float* __restrict__ hp,
                                            float* __restrict__ sm) {
  int p = blockIdx.x * 256 + threadIdx.x;
  int b = p >> 16, s = p & 65535;
  const float* hpb = hp + (size_t)b * Cn * HWn + s;
  float sum = 0.f, mx = 0.f;
  for (int c = 0; c < Cn; ++c) {
    float v = hpb[(size_t)c * HWn];
    sum += v; mx = fmaxf(mx, v);
  }
  sm[(size_t)(b * 2 + 0) * HWn + s] = sum * (1.0f / 192.0f);
  sm[(size_t)(b * 2 + 1) * HWn + s] = mx;
}

// K6: channel attention MLP -> w1[b,c]
__global__ __launch_bounds__(256) void k_chatt(const float* __restrict__ ca_sum,
                                               const float* __restrict__ ca_max,
                                               const float* __restrict__ w1m,
                                               const float* __restrict__ w2m,
                                               float* __restrict__ w1out) {
  __shared__ float hid2[2][2][12];
  int tid = threadIdx.x;
  if (tid < 48) {
    int b = tid / 24, rem = tid % 24, pool = rem / 12, j = rem % 12;
    const float* src = pool ? ca_max : ca_sum;
    float scale = pool ? 1.0f : (1.0f / 65536.0f);
    float acc = 0.f;
    for (int c = 0; c < Cn; ++c) acc += src[b * Cn + c] * scale * w1m[j * Cn + c];
    hid2[b][pool][j] = fmaxf(acc, 0.f);
  }
  __syncthreads();
  for (int u = tid; u < 2 * Cn; u += 256) {
    int b = u / Cn, c = u % Cn;
    float acc = 0.f;
    #pragma unroll
    for (int j = 0; j < 12; ++j)
      acc += (hid2[b][0][j] + hid2[b][1][j]) * w2m[c * 12 + j];
    w1out[b * Cn + c] = 1.0f / (1.0f + expf(-acc));
  }
}

// K7: spatial attention -> w2[b,y,x]
__global__ __launch_bounds__(256) void k_spatt(const float* __restrict__ sm,
                                               const float* __restrict__ w3,
                                               const float* __restrict__ w5,
                                               const float* __restrict__ w7,
                                               float* __restrict__ w2out) {
  int p = blockIdx.x * 256 + threadIdx.x;
  int b = p >> 16, s = p & 65535;
  int y = s >> 8, x = s & 255;
  float acc = 0.f;
  for (int ic = 0; ic < 2; ++ic) {
    const float* in = sm + (size_t)(b * 2 + ic) * HWn;
    for (int dy = -3; dy <= 3; ++dy) {
      int yy = y + dy; if (yy < 0 || yy > 255) continue;
      for (int dx = -3; dx <= 3; ++dx) {
        int xx = x + dx; if (xx < 0 || xx > 255) continue;
        float v = in[yy * 256 + xx];
        acc += v * w7[ic * 49 + (dy + 3) * 7 + (dx + 3)];
        if (dy >= -2 && dy <= 2 && dx >= -2 && dx <= 2)
          acc += v * w5[ic * 25 + (dy + 2) * 5 + (dx + 2)];
        if (dy >= -1 && dy <= 1 && dx >= -1 && dx <= 1)
          acc += v * w3[ic * 9 + (dy + 1) * 3 + (dx + 1)];
      }
    }
  }
  w2out[p] = 1.0f / (1.0f + expf(-acc));
}

// K_bias: rel-pos MLP bias table [NH][64][64]
__global__ __launch_bounds__(256) void k_bias(const float* __restrict__ mw1,
                                              const float* __restrict__ mb1,
                                              const float* __restrict__ mw2,
                                              const float* __restrict__ mb2,
                                              float* __restrict__ biasTab) {
  int pair = blockIdx.x * 256 + threadIdx.x;
  int n = pair >> 6, m = pair & 63;
  float dr = (float)((n >> 3) - (m >> 3));
  float dc = (float)((n & 7) - (m & 7));
  float r0 = copysignf(log1pf(fabsf(dr)), dr);
  float r1 = copysignf(log1pf(fabsf(dc)), dc);
  float acc[6];
  #pragma unroll
  for (int h = 0; h < 6; ++h) acc[h] = mb2[h];
  for (int j = 0; j < 256; ++j) {
    float hv = fmaxf(r0 * mw1[j * 2] + r1 * mw1[j * 2 + 1] + mb1[j], 0.f);
    #pragma unroll
    for (int h = 0; h < 6; ++h) acc[h] += hv * mw2[h * 256 + j];
  }
  #pragma unroll
  for (int h = 0; h < 6; ++h) biasTab[h * 4096 + n * 64 + m] = acc[h];
}

// K_wt: transpose the 4 1x1-conv weight matrices to k-major Wt[c][o]
// so a wave's per-k weight slab (24 contiguous o) is one scalar-load run.
__global__ __launch_bounds__(256) void k_wt(const float* __restrict__ qw,
                                            const float* __restrict__ kw,
                                            const float* __restrict__ vw,
                                            const float* __restrict__ pw,
                                            float* __restrict__ wt) {
  int i = blockIdx.x * 256 + threadIdx.x;     // < 4*36864
  int m = i / 36864, r = i - m * 36864;
  int o = r / 192, c = r - o * 192;
  const float* s = (m == 0) ? qw : (m == 1) ? kw : (m == 2) ? vw : pw;
  wt[m * 36864 + c * 192 + o] = s[o * 192 + c];
}

// Core fp32 GEMM micro-loop: wave-uniform weight slab (24 out-ch, k-major,
// scalar-load path via readfirstlane-uniform o0), per-lane pixel from LDS.
// unroll 4: ~192 FMA cycles of independent work in flight per load group,
// covering the ~200cyc K$ s_load latency that capped VALUBusy at 55%.
__device__ __forceinline__ void gemm24(const float* __restrict__ xsp,
                                       const float* __restrict__ wp,
                                       const float* __restrict__ bias,
                                       int o0, int lane, float acc[24]) {
  #pragma unroll
  for (int i = 0; i < 24; ++i) acc[i] = bias[o0 + i];
  #pragma unroll 4
  for (int k = 0; k < 192; ++k) {
    float xv = xsp[(k << 6) + lane];
    const float4* wr = (const float4*)(wp + k * 192 + o0);   // uniform addr
    #pragma unroll
    for (int j = 0; j < 6; ++j) {
      float4 w4 = wr[j];
      acc[4 * j + 0] = fmaf(w4.x, xv, acc[4 * j + 0]);
      acc[4 * j + 1] = fmaf(w4.y, xv, acc[4 * j + 1]);
      acc[4 * j + 2] = fmaf(w4.z, xv, acc[4 * j + 2]);
      acc[4 * j + 3] = fmaf(w4.w, xv, acc[4 * j + 3]);
    }
  }
}

// K9: fused LN + Q/K/V 1x1-conv GEMMs. One block per window, 512 thr = 8 waves.
// Staging gathers x*w1*w2 from spatial x, LayerNorms in LDS, then three
// k-loops. XCD swizzle: adjacent windows share the 128B cache lines of the
// 32B/row window gathers -> L2 hits instead of HBM re-fetch.
// hp / Vsp alias (same buffer): each address is read (Q epi) then written
// (V epi) by the SAME thread -> no __restrict__ on those two, order is safe.
__global__ __launch_bounds__(512) void k_qkv(const float* __restrict__ x,
                                             const float* __restrict__ w1v,
                                             const float* __restrict__ w2v,
                                             const float* __restrict__ lnw,
                                             const float* __restrict__ lnb,
                                             const float* __restrict__ wt,
                                             const float* __restrict__ qb,
                                             const float* __restrict__ kb,
                                             const float* __restrict__ vb,
                                             const float* hp,
                                             float* Qo, float* Ko,
                                             float* Vsoa, float* Vsp) {
  __shared__ float xs[Cn][64];
  __shared__ float ps[8][64], pq[8][64], mu[64], inv[64];
  const int w = xswz(blockIdx.x, NWIN);
  const int b = w >> 10, wi = w & 1023;
  const int wy = wi >> 5, wx = wi & 31;
  const int t = threadIdx.x;
  // ---- stage x*w1*w2 into xs[c][n] ----
  #pragma unroll
  for (int r = 0; r < 6; ++r) {
    int u4 = t + (r << 9);               // < 3072 float4s
    int f = u4 << 2;
    int c = f >> 6, n0 = f & 63;
    int y = (wy << 3) + (n0 >> 3), xx = (wx << 3) + (n0 & 7);
    const float4 xv = *(const float4*)&x[(((size_t)(b * Cn + c)) << 16) + y * 256 + xx];
    const float4 wv = *(const float4*)&w2v[((size_t)b << 16) + y * 256 + xx];
    float w1c = w1v[b * Cn + c];
    float4 v;
    v.x = xv.x * w1c * wv.x; v.y = xv.y * w1c * wv.y;
    v.z = xv.z * w1c * wv.z; v.w = xv.w * w1c * wv.w;
    *(float4*)&xs[c][n0] = v;
  }
  __syncthreads();
  // ---- LN reduction: 8 partials x 24 channels per pixel ----
  {
    int n = t & 63, part = t >> 6;
    float s = 0.f, ss = 0.f;
    #pragma unroll
    for (int cc = 0; cc < 24; ++cc) {
      float v = xs[part * 24 + cc][n];
      s += v; ss += v * v;
    }
    ps[part][n] = s; pq[part][n] = ss;
  }
  __syncthreads();
  if (t < 64) {
    float s = 0.f, q = 0.f;
    #pragma unroll
    for (int p = 0; p < 8; ++p) { s += ps[p][t]; q += pq[p][t]; }
    float m = s * (1.0f / 192.0f);
    float var = q * (1.0f / 192.0f) - m * m;
    mu[t] = m; inv[t] = rsqrtf(var + 1e-5f);
  }
  __syncthreads();
  // ---- normalize in place ----
  #pragma unroll
  for (int r = 0; r < 6; ++r) {
    int u4 = t + (r << 9);
    int f = u4 << 2;
    int c = f >> 6, n0 = f & 63;
    float4 v = *(float4*)&xs[c][n0];
    float lw = lnw[c], lb = lnb[c];
    float4 o;
    o.x = (v.x - mu[n0 + 0]) * inv[n0 + 0] * lw + lb;
    o.y = (v.y - mu[n0 + 1]) * inv[n0 + 1] * lw + lb;
    o.z = (v.z - mu[n0 + 2]) * inv[n0 + 2] * lw + lb;
    o.w = (v.w - mu[n0 + 3]) * inv[n0 + 3] * lw + lb;
    *(float4*)&xs[c][n0] = o;
  }
  __syncthreads();
  // ---- GEMMs ----
  const int lane = t & 63;
  const int wv = __builtin_amdgcn_readfirstlane(t >> 6);
  const int o0 = wv * 24;
  const int y = (wy << 3) + (lane >> 3), xxp = (wx << 3) + (lane & 7);
  const int sOff = y * 256 + xxp;
  const size_t soa = (size_t)w * 12288 + (size_t)o0 * 64 + lane;
  const size_t sp = (((size_t)(b * Cn + o0)) << 16) + sOff;
  float acc[24];
  // ---- Q = conv1x1 + prompt(hp) ----
  gemm24(&xs[0][0], wt, qb, o0, lane, acc);
  #pragma unroll
  for (int i = 0; i < 24; ++i)
    Qo[soa + (size_t)(i << 6)] = acc[i] + hp[sp + ((size_t)i << 16)];
  // ---- K ----
  gemm24(&xs[0][0], wt + 36864, kb, o0, lane, acc);
  #pragma unroll
  for (int i = 0; i < 24; ++i)
    Ko[soa + (size_t)(i << 6)] = acc[i];
  // ---- V (SoA + spatial) ----
  gemm24(&xs[0][0], wt + 2 * 36864, vb, o0, lane, acc);
  #pragma unroll
  for (int i = 0; i < 24; ++i) {
    Vsoa[soa + (size_t)(i << 6)] = acc[i];
    Vsp[sp + ((size_t)i << 16)] = acc[i];
  }
}

// K12: proj GEMM. Input tile = attn_out(SoA) + conv_out(spatial) staged in
// LDS; identity epilogue (+ x*w1*w2); spatial output. XCD swizzle for the
// spatial gathers/stores (same mechanism as k_qkv).
__global__ __launch_bounds__(512) void k_proj(const float* __restrict__ attn,
                                              const float* __restrict__ conv,
                                              const float* __restrict__ wtp,
                                              const float* __restrict__ pb,
                                              const float* __restrict__ resx,
                                              const float* __restrict__ rw1,
                                              const float* __restrict__ rw2,
                                              float* __restrict__ out) {
  __shared__ float xs[Cn][64];
  const int w = xswz(blockIdx.x, NWIN);
  const int b = w >> 10, wi = w & 1023;
  const int wy = wi >> 5, wx = wi & 31;
  const int t = threadIdx.x;
  const float4* av = (const float4*)(attn + (size_t)w * 12288);
  #pragma unroll
  for (int r = 0; r < 6; ++r) {
    int u4 = t + (r << 9);
    int f = u4 << 2;
    int c = f >> 6, n0 = f & 63;
    int yy = (wy << 3) + (n0 >> 3), xx = (wx << 3) + (n0 & 7);
    float4 a = av[u4];
    float4 cv = *(const float4*)&conv[(((size_t)(b * Cn + c)) << 16) + yy * 256 + xx];
    a.x += cv.x; a.y += cv.y; a.z += cv.z; a.w += cv.w;
    *(float4*)&xs[c][n0] = a;
  }
  __syncthreads();
  const int lane = t & 63;
  const int wv = __builtin_amdgcn_readfirstlane(t >> 6);
  const int o0 = wv * 24;
  const int y = (wy << 3) + (lane >> 3), xxp = (wx << 3) + (lane & 7);
  const int sOff = y * 256 + xxp;
  float acc[24];
  gemm24(&xs[0][0], wtp, pb, o0, lane, acc);
  const float w2s = rw2[((size_t)b << 16) + sOff];
  const size_t sp = (((size_t)(b * Cn + o0)) << 16) + sOff;
  #pragma unroll
  for (int i = 0; i < 24; ++i) {
    float idv = resx[sp + ((size_t)i << 16)] * rw1[b * Cn + o0 + i] * w2s;
    out[sp + ((size_t)i << 16)] = acc[i] + idv;
  }
}

// K10: window attention, one block per (window, head). All tensors window-SoA.
// XCD swizzle keeps a window's blocks near each other in issue order.
// out may alias V (block fully stages q/k/v in LDS before storing).
__global__ __launch_bounds__(256) void k_attn(const float* Q,
                                              const float* Kt,
                                              const float* V,
                                              const float* __restrict__ biasTab,
                                              float* out) {
  __shared__ float qt[64][36];     // [n][d], padded
  __shared__ float kt[64][36];     // [m][d]
  __shared__ float vl[2048];       // [d][m] flat
  __shared__ float pb[64][65];     // bias tile then softmax probs [n][m]
  const int blk = xswz(blockIdx.x, NWIN * 6);  // < 2048*6
  const int h = blk % 6, w = blk / 6;
  const int t = threadIdx.x;
  const size_t base = ((size_t)w * Cn + h * 32) * 64;
  const float4* Qg = (const float4*)(Q + base);
  const float4* Kg = (const float4*)(Kt + base);
  const float4* Vg = (const float4*)(V + base);
  #pragma unroll
  for (int r = 0; r < 2; ++r) {
    int i4 = t + (r << 8);          // < 512
    int f = i4 << 2;
    int d = f >> 6, n = f & 63;
    float4 q4 = Qg[i4], k4 = Kg[i4], v4 = Vg[i4];
    qt[n + 0][d] = q4.x * 0.17677669529663687f;
    qt[n + 1][d] = q4.y * 0.17677669529663687f;
    qt[n + 2][d] = q4.z * 0.17677669529663687f;
    qt[n + 3][d] = q4.w * 0.17677669529663687f;
    kt[n + 0][d] = k4.x; kt[n + 1][d] = k4.y;
    kt[n + 2][d] = k4.z; kt[n + 3][d] = k4.w;
    ((float4*)vl)[i4] = v4;
  }
  const float4* Bg = (const float4*)(biasTab + h * 4096);
  #pragma unroll
  for (int r = 0; r < 4; ++r) {
    int i4 = t + (r << 8);          // < 1024
    int f = i4 << 2;
    int n = f >> 6, m = f & 63;
    float4 b4 = Bg[i4];
    pb[n][m + 0] = b4.x; pb[n][m + 1] = b4.y;
    pb[n][m + 2] = b4.z; pb[n][m + 3] = b4.w;
  }
  __syncthreads();
  // ---- QK^T + bias: thread (n = t>>2, 16 m's = (t&3)*16+j) ----
  const int n = t >> 2, m0 = (t & 3) << 4;
  float sc[16];
  #pragma unroll
  for (int j = 0; j < 16; ++j) sc[j] = pb[n][m0 + j];
  #pragma unroll
  for (int d4 = 0; d4 < 32; d4 += 4) {
    float4 qv = *(const float4*)&qt[n][d4];
    #pragma unroll
    for (int j = 0; j < 16; ++j) {
      float4 kv = *(const float4*)&kt[m0 + j][d4];
      sc[j] += qv.x * kv.x + qv.y * kv.y + qv.z * kv.z + qv.w * kv.w;
    }
  }
  // ---- softmax across the 4 lanes sharing row n ----
  float mx = sc[0];
  #pragma unroll
  for (int j = 1; j < 16; ++j) mx = fmaxf(mx, sc[j]);
  mx = fmaxf(mx, __shfl_xor(mx, 1));
  mx = fmaxf(mx, __shfl_xor(mx, 2));
  float ssum = 0.f;
  #pragma unroll
  for (int j = 0; j < 16; ++j) { sc[j] = __expf(sc[j] - mx); ssum += sc[j]; }
  ssum += __shfl_xor(ssum, 1);
  ssum += __shfl_xor(ssum, 2);
  float sinv = 1.0f / ssum;
  #pragma unroll
  for (int j = 0; j < 16; ++j) sc[j] *= sinv;
  __syncthreads();   // all bias reads done before overwrite
  #pragma unroll
  for (int j = 0; j < 16; ++j) pb[n][m0 + j] = sc[j];
  __syncthreads();
  // ---- PV: thread (nn = t&63, 8 d's = (t>>6)*8..) ----
  const int nn = t & 63, dp = (t >> 6) << 3;
  float o[8];
  #pragma unroll
  for (int dd = 0; dd < 8; ++dd) o[dd] = 0.f;
  #pragma unroll
  for (int mc = 0; mc < 16; ++mc) {
    int m = mc << 2;
    float p0 = pb[nn][m], p1 = pb[nn][m + 1], p2 = pb[nn][m + 2], p3 = pb[nn][m + 3];
    #pragma unroll
    for (int dd = 0; dd < 8; ++dd) {
      float4 vv = *(const float4*)&vl[((dp + dd) << 6) + m];
      o[dd] += p0 * vv.x + p1 * vv.y + p2 * vv.z + p3 * vv.w;
    }
  }
  #pragma unroll
  for (int dd = 0; dd < 8; ++dd)
    out[base + (size_t)(dp + dd) * 64 + nn] = o[dd];
}

// K11: depthwise 5x5 reflect conv on spatial V -> conv_out (spatial)
__global__ __launch_bounds__(256) void k_dw(const float* __restrict__ V,
                                            const float* __restrict__ dww,
                                            const float* __restrict__ dwb,
                                            float* __restrict__ co) {
  size_t idx = (size_t)blockIdx.x * 256 + threadIdx.x;
  int s = (int)(idx & 65535);
  int bc = (int)(idx >> 16);
  int c = bc % Cn;
  int y = s >> 8, x = s & 255;
  const float* vb = V + ((size_t)bc << 16);
  float acc = dwb[c];
  #pragma unroll
  for (int dy = -2; dy <= 2; ++dy) {
    int yy = y + dy;
    yy = yy < 0 ? -yy : (yy > 255 ? 510 - yy : yy);
    #pragma unroll
    for (int dx = -2; dx <= 2; ++dx) {
      int xx = x + dx;
      xx = xx < 0 ? -xx : (xx > 255 ? 510 - xx : xx);
      acc += vb[yy * 256 + xx] * dww[c * 25 + (dy + 2) * 5 + (dx + 2)];
    }
  }
  co[idx] = acc;
}

extern "C" void kernel_launch(void* const* d_in, const int* in_sizes, int n_in,
                              void* d_out, int out_size, void* d_ws, size_t ws_size,
                              hipStream_t stream) {
  const float* x      = (const float*)d_in[0];
  const float* ln_w   = (const float*)d_in[1];
  const float* ln_b   = (const float*)d_in[2];
  const float* ca_w1  = (const float*)d_in[3];
  const float* ca_w2  = (const float*)d_in[4];
  const float* sa_w3  = (const float*)d_in[5];
  const float* sa_w5  = (const float*)d_in[6];
  const float* sa_w7  = (const float*)d_in[7];
  const float* q_w    = (const float*)d_in[8];
  const float* q_b    = (const float*)d_in[9];
  const float* k_w    = (const float*)d_in[10];
  const float* k_b    = (const float*)d_in[11];
  const float* v_w    = (const float*)d_in[12];
  const float* v_b    = (const float*)d_in[13];
  const float* proj_w = (const float*)d_in[14];
  const float* proj_b = (const float*)d_in[15];
  const float* meta_w1 = (const float*)d_in[16];
  const float* meta_b1 = (const float*)d_in[17];
  const float* meta_w2 = (const float*)d_in[18];
  const float* meta_b2 = (const float*)d_in[19];
  const float* dw_w   = (const float*)d_in[20];
  const float* dw_b   = (const float*)d_in[21];

  float* ws = (float*)d_ws;
  const size_t N = (size_t)NPIX;
  // Overlay (peak 3N + small):
  //  buf0: V-SoA -> attn_out (in-place)
  //  buf1: K(SoA) -> conv_out (spatial)
  //  buf2: hp (spatial) -> V-spatial (per-window thread-local RAW, safe)
  //  d_out: Q(SoA) -> final output (spatial)
  float* buf0 = ws;
  float* buf1 = ws + N;
  float* buf2 = ws + 2 * N;
  float* smallb = ws + 3 * N;
  float* ca_sum  = smallb;
  float* ca_max  = smallb + 384;
  float* w1v     = smallb + 768;
  float* smb     = smallb + 1152;
  float* w2v     = smb + 262144;
  float* biasTab = w2v + 131072;
  float* wt4     = biasTab + 24576;   // 4 * 192*192 transposed weights
  float* gaBuf   = wt4 + 147456;      // 256 complex spatial gaussian taps

  float* hp = buf2;
  float* Kb = buf1;
  float* Qb = (float*)d_out;
  float* Vsoa = buf0;
  float* Vsp  = buf2;
  float* attn_out = buf0;
  float* conv_out = buf1;

  k_zero<<<3, 256, 0, stream>>>(ca_sum, 768);
  k_ga<<<1, 256, 0, stream>>>((float2*)gaBuf);
  // fused separable gaussian blur -> hp + ca stats (x read once, all in LDS)
  k_gblur<<<384 * 32, 256, 0, stream>>>(x, (const float2*)gaBuf, hp, ca_sum, ca_max);
  k_sm<<<Bn * HWn / 256, 256, 0, stream>>>(hp, smb);
  k_chatt<<<1, 256, 0, stream>>>(ca_sum, ca_max, ca_w1, ca_w2, w1v);
  k_spatt<<<Bn * HWn / 256, 256, 0, stream>>>(smb, sa_w3, sa_w5, sa_w7, w2v);
  k_bias<<<16, 256, 0, stream>>>(meta_w1, meta_b1, meta_w2, meta_b2, biasTab);
  k_wt<<<576, 256, 0, stream>>>(q_w, k_w, v_w, proj_w, wt4);
  // fused LN + Q/K/V: Q(+hp)->d_out, K->buf1, V->buf0+buf2(spatial)
  k_qkv<<<NWIN, 512, 0, stream>>>(x, w1v, w2v, ln_w, ln_b, wt4, q_b, k_b, v_b,
                                  hp, Qb, Kb, Vsoa, Vsp);
  k_attn<<<NWIN * 6, 256, 0, stream>>>(Qb, Kb, Vsoa, biasTab, attn_out);
  k_dw<<<NPIX / 256, 256, 0, stream>>>(Vsp, dw_w, dw_b, conv_out);
  // proj GEMM: input tile = attn_out(SoA) + conv_out(spatial), identity
  // epilogue, spatial output.
  k_proj<<<NWIN, 512, 0, stream>>>(attn_out, conv_out, wt4 + 3 * 36864, proj_b,
                                   x, w1v, w2v, (float*)d_out);
}